// Round 6
// baseline (254.987 us; speedup 1.0000x reference)
//
#include <hip/hip_runtime.h>

#define PP 96
#define NB (PP*PP)            // 9216
#define NCH (NB/64)           // 144 64-chunks
#define PROB_THR 0.9f
#define IOU_THR 0.5f
#define SORT_CAP 2048         // fast path capacity (W <= 32)
#define NPROD 64              // producer blocks, 32 rows each = 2048
#define MAGIC 0x7A11C0DE

typedef unsigned long long u64;

// Bit-identical decode (no FMA contraction; rintf == round-half-even == jnp.round).
__device__ __forceinline__ void decode_box(const float* __restrict__ x, int n,
                                           float& X1, float& Y1, float& X2, float& Y2)
{
    float xv = x[NB + n];
    float yv = x[2 * NB + n];
    float wv = x[3 * NB + n];
    float hv = x[4 * NB + n];
    int i = n / PP;
    int j = n - i * PP;
    float bx = __fadd_rn(__fmul_rn(xv, 16.0f), (float)i * 16.0f);
    float by = __fadd_rn(__fmul_rn(yv, 16.0f), (float)j * 16.0f);
    float bw = __fmul_rn(wv, 1536.0f);
    float bh = __fmul_rn(hv, 1536.0f);
    X1 = rintf(bx);
    Y1 = rintf(by);
    X2 = rintf(__fadd_rn(bw, bx));
    Y2 = rintf(__fadd_rn(bh, by));
}

// Exact-equivalent IoU>0.5 test without division. All quantities are exact
// integers in f32 (coords <= 3072, areas <= 1537^2, union < 2^23), and
// fl(inter/uni) > 0.5  <=>  inter+inter > uni  (margin 1/(2u) > 2^-24 > ulp/2).
__device__ __forceinline__ int iou_hit_nodiv(float ix1, float iy1, float ix2, float iy2, float iar,
                                             float jx1, float jy1, float jx2, float jy2, float jar)
{
    float xx1 = fmaxf(ix1, jx1), yy1 = fmaxf(iy1, jy1);
    float xx2 = fminf(ix2, jx2), yy2 = fminf(iy2, jy2);
    float iw = fmaxf(__fsub_rn(xx2, xx1), 0.0f);
    float ih = fmaxf(__fsub_rn(yy2, yy1), 0.0f);
    float inter = __fmul_rn(iw, ih);
    float uni = __fsub_rn(__fadd_rn(iar, jar), inter);
    return (uni > 0.0f && __fadd_rn(inter, inter) > uni) ? 1 : 0;
}

__device__ __forceinline__ int iou_hit_div(float ix1, float iy1, float ix2, float iy2, float iar,
                                           float jx1, float jy1, float jx2, float jy2, float jar)
{
    float xx1 = fmaxf(ix1, jx1), yy1 = fmaxf(iy1, jy1);
    float xx2 = fminf(ix2, jx2), yy2 = fminf(iy2, jy2);
    float iw = fmaxf(__fsub_rn(xx2, xx1), 0.0f);
    float ih = fmaxf(__fsub_rn(yy2, yy1), 0.0f);
    float inter = __fmul_rn(iw, ih);
    float uni = __fsub_rn(__fadd_rn(iar, jar), inter);
    return (uni > 0.0f && __fdiv_rn(inter, uni) > IOU_THR) ? 1 : 0;
}

// ---------------------------------------------------------------------------
// Single fused kernel, 65 blocks x 256.
// Blocks 0..63: (if fast & has rows) local prep (compact+sort+decode in LDS),
//   write 32 adjacency rows, fence, release MAGIC flag. Else flag immediately.
// Block 64: local prep, spin on 64 flags, LDS-dbuf register sweep over adj
//   (plain batched loads), emit ALL output rows. Slow fallback for M>2048.
// ---------------------------------------------------------------------------
__global__ void __launch_bounds__(256) k_fused(
    const float* __restrict__ x, float* __restrict__ out,
    int* __restrict__ flags,
    u64* __restrict__ skeys,
    float* __restrict__ gss,
    float* __restrict__ gx1, float* __restrict__ gy1,
    float* __restrict__ gx2, float* __restrict__ gy2,
    u64* __restrict__ adj, long long cap_words)
{
    __shared__ u64 lmask[NCH];
    __shared__ int loff[NCH];
    __shared__ int sM;
    __shared__ u64 kdb[SORT_CAP];                       // keys -> sweep dbuf
    __shared__ float bx1[SORT_CAP], by1[SORT_CAP], bx2[SORT_CAP], by2[SORT_CAP], bss[SORT_CAP];

    const int tid = threadIdx.x;
    const int lane = tid & 63;
    const int wv = tid >> 6;
    const int b = blockIdx.x;

    // ---- validity masks (coalesced score reads) ----
    for (int c = wv; c < NCH; c += 4) {
        float s = x[(c << 6) + lane];
        u64 m = __ballot(s > PROB_THR);
        if (lane == 0) lmask[c] = m;
    }
    __syncthreads();
    if (tid < NCH) {
        int off = 0;
        for (int q = 0; q < tid; ++q) off += __popcll(lmask[q]);
        loff[tid] = off;
        if (tid == NCH - 1) sM = off + __popcll(lmask[NCH - 1]);
    }
    __syncthreads();
    const int M = sM;
    const int W = (M + 63) >> 6;
    const long long R = (long long)(((M + 31) >> 5) << 5);
    const bool fast = (M <= SORT_CAP) && (R * W + 64 <= cap_words);
    const bool doPrep = fast && (b == NPROD || (b << 5) < M);   // block-uniform

    if (doPrep) {
        // compact keys (score-bits<<32 | NB-1-n : unique, total order)
        for (int c = wv; c < NCH; c += 4) {
            float s = x[(c << 6) + lane];            // L1-hot
            u64 m = lmask[c];
            if ((m >> lane) & 1ull) {
                int pos = loff[c] + __popcll(m & ((1ull << lane) - 1ull));
                int n = (c << 6) + lane;
                kdb[pos] = ((u64)__float_as_uint(s) << 32) | (u64)(NB - 1 - n);
            }
        }
        for (int q = M + tid; q < SORT_CAP; q += 256) kdb[q] = 0ull;
        __syncthreads();
        // bitonic sort, descending (keys unique -> deterministic, == argsort)
        for (int k = 2; k <= SORT_CAP; k <<= 1) {
            for (int j = k >> 1; j > 0; j >>= 1) {
                for (int p = tid; p < SORT_CAP; p += 256) {
                    int q2 = p ^ j;
                    if (q2 > p) {
                        u64 a = kdb[p], c2 = kdb[q2];
                        if ((a < c2) == ((p & k) == 0)) { kdb[p] = c2; kdb[q2] = a; }
                    }
                }
                __syncthreads();
            }
        }
        // decode sorted boxes into LDS
        for (int r = tid; r < M; r += 256) {
            u64 key = kdb[r];
            int n = NB - 1 - (int)(key & 0xFFFFFFFFull);
            float X1, Y1, X2, Y2;
            decode_box(x, n, X1, Y1, X2, Y2);
            bx1[r] = X1; by1[r] = Y1; bx2[r] = X2; by2[r] = Y2;
            bss[r] = __uint_as_float((unsigned)(key >> 32));
        }
        __syncthreads();
    }

    // ======================= producer blocks =======================
    if (b < NPROD) {
        if (doPrep) {
            for (int ri = 0; ri < 8; ++ri) {
                int i = (b << 5) + (ri << 2) + wv;
                if (i >= M) break;                   // per-wave; no sync below until fence
                float ix1 = bx1[i], iy1 = by1[i], ix2 = bx2[i], iy2 = by2[i];
                float iar = __fmul_rn(__fsub_rn(ix2, ix1), __fsub_rn(iy2, iy1));
                for (int kk = 0; kk < W; ++kk) {
                    int j = (kk << 6) + lane;
                    float jx1 = bx1[j], jy1 = by1[j], jx2 = bx2[j], jy2 = by2[j];
                    float jar = __fmul_rn(__fsub_rn(jx2, jx1), __fsub_rn(jy2, jy1));
                    int hit = (j < M) && iou_hit_nodiv(ix1, iy1, ix2, iy2, iar,
                                                       jx1, jy1, jx2, jy2, jar);
                    u64 mm = __ballot(hit);
                    if (lane == 0) adj[(size_t)i * W + kk] = mm;
                }
            }
            __threadfence();                         // push adj to agent coherence point
            __syncthreads();
        }
        if (tid == 0)
            __hip_atomic_store(&flags[b], MAGIC, __ATOMIC_RELEASE, __HIP_MEMORY_SCOPE_AGENT);
        return;
    }

    // ======================= consumer block ========================
    if (fast) {
        if (tid < 64) {
            // spin: lane l polls flags[l]; all 64 producers always flag
            for (;;) {
                int f = __hip_atomic_load(&flags[lane], __ATOMIC_ACQUIRE,
                                          __HIP_MEMORY_SCOPE_AGENT);
                if (__all(f == MAGIC)) break;
                __builtin_amdgcn_s_sleep(8);
            }
            // LDS double-buffered register sweep (kdb reused as dbuf)
            int wl = (lane < W) ? lane : 0;
            u64 sup = 0ull, dec = 0ull, mykw = 0ull;
            int nrb = (M + 31) >> 5;
            int nw = (32 * W + 63) >> 6;             // <= 16 lane-sliced u64
            u64 pre[16];
            if (nrb > 0) {
                for (int q = 0; q < nw; ++q) pre[q] = adj[q * 64 + lane];
                for (int q = 0; q < nw; ++q) kdb[q * 64 + lane] = pre[q];
            }
            for (int rb = 0; rb < nrb; ++rb) {
                int c = rb >> 1;
                u64* bp = kdb + (size_t)(rb & 1) * 1024;
                bool pf = (rb + 1 < nrb);
                if (pf) {                            // batched plain prefetch
                    size_t boff = (size_t)(rb + 1) * 32 * W;
                    for (int q = 0; q < nw; ++q) pre[q] = adj[boff + q * 64 + lane];
                }
                if (!(rb & 1)) dec = (rb == 0) ? 0ull : (u64)__shfl((unsigned long long)sup, c);
                int rem = M - (c << 6);
                if (rem < 64) dec |= (~0ull) << rem;
                int sh = (rb & 1) << 5;
                u64 kw = 0ull;
                for (int sc = 0; sc < 4; ++sc) {
                    u64 colb[8], rowb[8];
                    #pragma unroll
                    for (int t = 0; t < 8; ++t) {
                        int row = sc * 8 + t;
                        colb[t] = bp[row * W + c];
                        rowb[t] = bp[row * W + wl];
                    }
                    #pragma unroll
                    for (int t = 0; t < 8; ++t) {
                        int tt = sc * 8 + t;
                        u64 bbit = (dec >> (tt + sh)) & 1ull;
                        u64 m = bbit - 1ull;         // ~0 kept, 0 suppressed
                        dec |= colb[t] & m;
                        sup |= rowb[t] & m;
                        kw  |= m & (1ull << tt);
                    }
                }
                mykw |= (lane == c) ? (kw << sh) : 0ull;
                if (pf) {
                    u64* dst = kdb + (size_t)((rb + 1) & 1) * 1024;
                    for (int q = 0; q < nw; ++q) dst[q * 64 + lane] = pre[q];
                }
            }
            lmask[lane] = mykw;                      // keep word w (lmask is dead)
        }
        __syncthreads();
        // emit ALL rows (zeros for non-kept) — single-writer, no races
        for (int i = tid; i < NB; i += 256) {
            bool kept = (i < M) && ((lmask[i >> 6] >> (i & 63)) & 1ull);
            if (kept) {
                float a = bx1[i], b2 = by1[i], c2 = bx2[i], d = by2[i];
                out[i * 5 + 0] = bss[i];
                out[i * 5 + 1] = a;
                out[i * 5 + 2] = b2;
                out[i * 5 + 3] = __fsub_rn(c2, a);
                out[i * 5 + 4] = __fsub_rn(d, b2);
                out[5 * NB + i] = 1.0f;
            } else {
                out[i * 5 + 0] = 0.0f; out[i * 5 + 1] = 0.0f; out[i * 5 + 2] = 0.0f;
                out[i * 5 + 3] = 0.0f; out[i * 5 + 4] = 0.0f;
                out[5 * NB + i] = 0.0f;
            }
        }
        return;
    }

    // ---------------- slow fallback (M > SORT_CAP; never hit here) ----------------
    // 1. compact keys to global (order irrelevant for counting rank)
    for (int c = wv; c < NCH; c += 4) {
        float s = x[(c << 6) + lane];
        u64 m = lmask[c];
        if ((m >> lane) & 1ull) {
            int pos = loff[c] + __popcll(m & ((1ull << lane) - 1ull));
            int n = (c << 6) + lane;
            skeys[pos] = ((u64)__float_as_uint(s) << 32) | (u64)(NB - 1 - n);
        }
    }
    __threadfence_block();
    __syncthreads();
    // 2. counting rank + sorted scatter (O(M^2/256) — correctness-only path)
    for (int t = tid; t < M; t += 256) {
        u64 key = skeys[t];
        int r = 0;
        for (int q = 0; q < M; ++q) r += (skeys[q] > key) ? 1 : 0;
        int n = NB - 1 - (int)(key & 0xFFFFFFFFull);
        float X1, Y1, X2, Y2;
        decode_box(x, n, X1, Y1, X2, Y2);
        gss[r] = __uint_as_float((unsigned)(key >> 32));
        gx1[r] = X1; gy1[r] = Y1; gx2[r] = X2; gy2[r] = Y2;
    }
    __threadfence_block();
    __syncthreads();
    // 3. single-wave on-the-fly sweep (R1-validated logic)
    if (tid < 64) {
        u64 kbs[3] = {0ull, 0ull, 0ull};
        for (int i = 0; i < M; ++i) {
            float ix1 = gx1[i], iy1 = gy1[i], ix2 = gx2[i], iy2 = gy2[i];
            float iar = __fmul_rn(__fsub_rn(ix2, ix1), __fsub_rn(iy2, iy1));
            int hit = 0;
            int nk = (i > lane) ? ((i - lane + 63) >> 6) : 0;
            for (int w = 0; w < 3 && !hit; ++w) {
                int klim = nk - (w << 6);
                if (klim <= 0) break;
                u64 bits = kbs[w];
                if (klim < 64) bits &= ((1ull << klim) - 1ull);
                while (bits) {
                    int kk2 = __builtin_ctzll(bits);
                    bits &= bits - 1ull;
                    int jj = lane + (((w << 6) + kk2) << 6);
                    float jx1 = gx1[jj], jy1 = gy1[jj], jx2 = gx2[jj], jy2 = gy2[jj];
                    float jar = __fmul_rn(__fsub_rn(jx2, jx1), __fsub_rn(jy2, jy1));
                    if (iou_hit_div(ix1, iy1, ix2, iy2, iar, jx1, jy1, jx2, jy2, jar)) { hit = 1; break; }
                }
            }
            int suppressed = __any(hit);
            if (!suppressed && lane == (i & 63)) kbs[(i >> 6) >> 6] |= 1ull << ((i >> 6) & 63);
        }
        int NWrd = (M + 63) >> 6;                    // transpose to keep words
        for (int wd = 0; wd < NWrd; ++wd) {
            u64 bit = (kbs[wd >> 6] >> (wd & 63)) & 1ull;
            u64 word = __ballot(bit != 0);
            if (lane == 0 && wd < NCH) lmask[wd] = word;
        }
    }
    __syncthreads();
    for (int i = tid; i < NB; i += 256) {
        bool kept = (i < M) && ((lmask[i >> 6] >> (i & 63)) & 1ull);
        if (kept) {
            float a = gx1[i], b2 = gy1[i], c2 = gx2[i], d = gy2[i];
            out[i * 5 + 0] = gss[i];
            out[i * 5 + 1] = a;
            out[i * 5 + 2] = b2;
            out[i * 5 + 3] = __fsub_rn(c2, a);
            out[i * 5 + 4] = __fsub_rn(d, b2);
            out[5 * NB + i] = 1.0f;
        } else {
            out[i * 5 + 0] = 0.0f; out[i * 5 + 1] = 0.0f; out[i * 5 + 2] = 0.0f;
            out[i * 5 + 3] = 0.0f; out[i * 5 + 4] = 0.0f;
            out[5 * NB + i] = 0.0f;
        }
    }
}

extern "C" void kernel_launch(void* const* d_in, const int* in_sizes, int n_in,
                              void* d_out, int out_size, void* d_ws, size_t ws_size,
                              hipStream_t stream) {
    const float* x = (const float*)d_in[0];
    float* out = (float*)d_out;

    // Workspace: flags[64] ints | slow keys u64[NB] | slow sorted f32[NB]x5 | adj
    // Flags use a MAGIC sentinel so the 0xAA poison needs no pre-zeroing pass.
    char* ws = (char*)d_ws;
    int* flags = (int*)ws;                                    // 256 B
    u64* skeys = (u64*)(ws + 256);                            // 73728 B
    float* fb  = (float*)(ws + 256 + (size_t)NB * 8);
    float* gss = fb + 0 * NB;
    float* gx1 = fb + 1 * NB;
    float* gy1 = fb + 2 * NB;
    float* gx2 = fb + 3 * NB;
    float* gy2 = fb + 4 * NB;
    size_t adj_off = 256 + (size_t)NB * 8 + (size_t)5 * NB * 4;   // 258,304 B
    u64* adj = (u64*)(ws + adj_off);
    long long cap_words = (ws_size > adj_off) ? (long long)((ws_size - adj_off) / 8) : 0;

    k_fused<<<NPROD + 1, 256, 0, stream>>>(x, out, flags, skeys,
                                           gss, gx1, gy1, gx2, gy2,
                                           adj, cap_words);
}

// Round 7
// 229.156 us; speedup vs baseline: 1.1127x; 1.1127x over previous
//
#include <hip/hip_runtime.h>

#define PP 96
#define NB (PP*PP)            // 9216
#define NCH (NB/64)           // 144 64-chunks
#define PROB_THR 0.9f
#define SORT_CAP 2048         // fast path capacity (W <= 32)
#define NPROD 64              // producer blocks, 32 rows each = 2048

typedef unsigned long long u64;

// Bit-identical decode (no FMA contraction; rintf == round-half-even == jnp.round).
__device__ __forceinline__ void decode_box(const float* __restrict__ x, int n,
                                           float& X1, float& Y1, float& X2, float& Y2)
{
    float xv = x[NB + n];
    float yv = x[2 * NB + n];
    float wv = x[3 * NB + n];
    float hv = x[4 * NB + n];
    int i = n / PP;
    int j = n - i * PP;
    float bx = __fadd_rn(__fmul_rn(xv, 16.0f), (float)i * 16.0f);
    float by = __fadd_rn(__fmul_rn(yv, 16.0f), (float)j * 16.0f);
    float bw = __fmul_rn(wv, 1536.0f);
    float bh = __fmul_rn(hv, 1536.0f);
    X1 = rintf(bx);
    Y1 = rintf(by);
    X2 = rintf(__fadd_rn(bw, bx));
    Y2 = rintf(__fadd_rn(bh, by));
}

// Exact-equivalent IoU>0.5 without division (R5-validated): all quantities are
// exact integers in f32 (coords <= 3072, union < 2^23);
// fl(inter/uni) > 0.5 <=> inter+inter > uni (margin 1/(2u) > 2^-24 > ulp/2).
__device__ __forceinline__ int iou_hit_nodiv(float ix1, float iy1, float ix2, float iy2, float iar,
                                             float jx1, float jy1, float jx2, float jy2, float jar)
{
    float xx1 = fmaxf(ix1, jx1), yy1 = fmaxf(iy1, jy1);
    float xx2 = fminf(ix2, jx2), yy2 = fminf(iy2, jy2);
    float iw = fmaxf(__fsub_rn(xx2, xx1), 0.0f);
    float ih = fmaxf(__fsub_rn(yy2, yy1), 0.0f);
    float inter = __fmul_rn(iw, ih);
    float uni = __fsub_rn(__fadd_rn(iar, jar), inter);
    return (uni > 0.0f && __fadd_rn(inter, inter) > uni) ? 1 : 0;
}

__device__ __forceinline__ int iou_hit_div(float ix1, float iy1, float ix2, float iy2, float iar,
                                           float jx1, float jy1, float jx2, float jy2, float jar)
{
    float xx1 = fmaxf(ix1, jx1), yy1 = fmaxf(iy1, jy1);
    float xx2 = fminf(ix2, jx2), yy2 = fminf(iy2, jy2);
    float iw = fmaxf(__fsub_rn(xx2, xx1), 0.0f);
    float ih = fmaxf(__fsub_rn(yy2, yy1), 0.0f);
    float inter = __fmul_rn(iw, ih);
    float uni = __fsub_rn(__fadd_rn(iar, jar), inter);
    return (uni > 0.0f && __fdiv_rn(inter, uni) > 0.5f) ? 1 : 0;
}

// ---------------------------------------------------------------------------
// Dispatch 1: 64 blocks x 256. Active block b (rows b*32..b*32+31 < M):
// masks -> compact keys -> bitonic sort (dynamic pow2 size S >= M) -> decode
// boxes into LDS -> write 32 adjacency rows (plain stores; the dispatch
// boundary publishes them). Block 0 additionally writes M + sorted arrays
// (fast) or compacted keys (slow path).
// ---------------------------------------------------------------------------
__global__ void __launch_bounds__(256) k_prepadj(
    const float* __restrict__ x,
    float* __restrict__ gss,
    float* __restrict__ gx1, float* __restrict__ gy1,
    float* __restrict__ gx2, float* __restrict__ gy2,
    u64* __restrict__ skeys, int* __restrict__ counter,
    u64* __restrict__ adj, long long cap_words)
{
    __shared__ u64 lmask[NCH];
    __shared__ int loff[NCH];
    __shared__ int sM;
    __shared__ u64 kdb[SORT_CAP];
    __shared__ float bx1[SORT_CAP], by1[SORT_CAP], bx2[SORT_CAP], by2[SORT_CAP], bss[SORT_CAP];

    const int tid = threadIdx.x;
    const int lane = tid & 63;
    const int wv = tid >> 6;
    const int b = blockIdx.x;

    // validity masks (coalesced score reads)
    for (int c = wv; c < NCH; c += 4) {
        float s = x[(c << 6) + lane];
        u64 m = __ballot(s > PROB_THR);
        if (lane == 0) lmask[c] = m;
    }
    __syncthreads();
    if (tid < NCH) {
        int off = 0;
        for (int q = 0; q < tid; ++q) off += __popcll(lmask[q]);
        loff[tid] = off;
        if (tid == NCH - 1) sM = off + __popcll(lmask[NCH - 1]);
    }
    __syncthreads();
    const int M = sM;
    const int W = (M + 63) >> 6;
    const long long R = (long long)(((M + 31) >> 5) << 5);
    const bool fast = (M <= SORT_CAP) && (R * W + 64 <= cap_words);

    if (b == 0 && tid == 0) counter[0] = M;

    if (!fast) {
        if (b == 0) {       // publish compacted (unordered) keys for slow path
            for (int c = wv; c < NCH; c += 4) {
                float s = x[(c << 6) + lane];
                u64 m = lmask[c];
                if ((m >> lane) & 1ull) {
                    int pos = loff[c] + __popcll(m & ((1ull << lane) - 1ull));
                    int n = (c << 6) + lane;
                    skeys[pos] = ((u64)__float_as_uint(s) << 32) | (u64)(NB - 1 - n);
                }
            }
        }
        return;
    }
    if ((b << 5) >= M) return;          // no rows for this block (block-uniform)

    // compact keys into LDS
    for (int c = wv; c < NCH; c += 4) {
        float s = x[(c << 6) + lane];
        u64 m = lmask[c];
        if ((m >> lane) & 1ull) {
            int pos = loff[c] + __popcll(m & ((1ull << lane) - 1ull));
            int n = (c << 6) + lane;
            kdb[pos] = ((u64)__float_as_uint(s) << 32) | (u64)(NB - 1 - n);
        }
    }
    int S = 64; while (S < M) S <<= 1;  // dynamic sort size (pow2 >= M)
    for (int q = M + tid; q < S; q += 256) kdb[q] = 0ull;
    __syncthreads();
    // bitonic sort, descending (keys unique -> deterministic == argsort)
    for (int k = 2; k <= S; k <<= 1) {
        for (int j = k >> 1; j > 0; j >>= 1) {
            for (int p = tid; p < S; p += 256) {
                int q2 = p ^ j;
                if (q2 > p) {
                    u64 a = kdb[p], c2 = kdb[q2];
                    if ((a < c2) == ((p & k) == 0)) { kdb[p] = c2; kdb[q2] = a; }
                }
            }
            __syncthreads();
        }
    }
    // decode sorted boxes into LDS
    for (int r = tid; r < M; r += 256) {
        u64 key = kdb[r];
        int n = NB - 1 - (int)(key & 0xFFFFFFFFull);
        float X1, Y1, X2, Y2;
        decode_box(x, n, X1, Y1, X2, Y2);
        bx1[r] = X1; by1[r] = Y1; bx2[r] = X2; by2[r] = Y2;
        bss[r] = __uint_as_float((unsigned)(key >> 32));
    }
    __syncthreads();

    if (b == 0) {                       // publish sorted arrays for k_sweep
        for (int r = tid; r < M; r += 256) {
            gss[r] = bss[r];
            gx1[r] = bx1[r]; gy1[r] = by1[r];
            gx2[r] = bx2[r]; gy2[r] = by2[r];
        }
    }

    // adjacency rows owned by this block (R5-validated)
    for (int ri = 0; ri < 8; ++ri) {
        int i = (b << 5) + (ri << 2) + wv;
        if (i >= M) break;
        float ix1 = bx1[i], iy1 = by1[i], ix2 = bx2[i], iy2 = by2[i];
        float iar = __fmul_rn(__fsub_rn(ix2, ix1), __fsub_rn(iy2, iy1));
        for (int kk = 0; kk < W; ++kk) {
            int j = (kk << 6) + lane;
            float jx1 = bx1[j], jy1 = by1[j], jx2 = bx2[j], jy2 = by2[j];
            float jar = __fmul_rn(__fsub_rn(jx2, jx1), __fsub_rn(jy2, jy1));
            int hit = (j < M) && iou_hit_nodiv(ix1, iy1, ix2, iy2, iar,
                                               jx1, jy1, jx2, jy2, jar);
            u64 mm = __ballot(hit);
            if (lane == 0) adj[(size_t)i * W + kk] = mm;
        }
    }
}

// ---------------------------------------------------------------------------
// Dispatch 2: 1 block x 256. Fast: wave 0 runs the LDS double-buffered
// register sweep over adj (plain batched loads), then all threads emit every
// output row. Slow fallback (M > SORT_CAP): counting rank + decode + on-the-
// fly single-wave sweep (R1/R2-validated logic).
// ---------------------------------------------------------------------------
__global__ void __launch_bounds__(256) k_sweep(
    const float* __restrict__ x, float* __restrict__ out,
    float* __restrict__ gss,
    float* __restrict__ gx1, float* __restrict__ gy1,
    float* __restrict__ gx2, float* __restrict__ gy2,
    const u64* __restrict__ skeys, const int* __restrict__ counter,
    const u64* __restrict__ adj, long long cap_words)
{
    __shared__ u64 kdb[SORT_CAP];         // 16 KB sweep double-buffer
    __shared__ u64 keepw[NCH];
    int M = counter[0]; if (M > NB) M = NB;
    const int W = (M + 63) >> 6;
    const long long R = (long long)(((M + 31) >> 5) << 5);
    const bool fast = (M <= SORT_CAP) && (R * W + 64 <= cap_words);
    const int tid = threadIdx.x, lane = tid & 63;

    if (fast) {
        if (tid < 64) {
            int wl = (lane < W) ? lane : 0;
            u64 sup = 0ull, dec = 0ull, mykw = 0ull;
            int nrb = (M + 31) >> 5;
            int nw = (32 * W + 63) >> 6;          // <= 16 lane-sliced u64
            u64 pre[16];
            if (nrb > 0) {
                for (int q = 0; q < nw; ++q) pre[q] = adj[q * 64 + lane];
                for (int q = 0; q < nw; ++q) kdb[q * 64 + lane] = pre[q];
            }
            for (int rb = 0; rb < nrb; ++rb) {
                int c = rb >> 1;
                u64* bp = kdb + (size_t)(rb & 1) * 1024;
                bool pf = (rb + 1 < nrb);
                if (pf) {                          // batched plain prefetch
                    size_t boff = (size_t)(rb + 1) * 32 * W;
                    for (int q = 0; q < nw; ++q) pre[q] = adj[boff + q * 64 + lane];
                }
                if (!(rb & 1)) dec = (rb == 0) ? 0ull : (u64)__shfl((unsigned long long)sup, c);
                int rem = M - (c << 6);
                if (rem < 64) dec |= (~0ull) << rem;
                int sh = (rb & 1) << 5;
                u64 kw = 0ull;
                for (int sc = 0; sc < 4; ++sc) {
                    u64 colb[8], rowb[8];
                    #pragma unroll
                    for (int t = 0; t < 8; ++t) {
                        int row = sc * 8 + t;
                        colb[t] = bp[row * W + c];
                        rowb[t] = bp[row * W + wl];
                    }
                    #pragma unroll
                    for (int t = 0; t < 8; ++t) {
                        int tt = sc * 8 + t;
                        u64 bbit = (dec >> (tt + sh)) & 1ull;
                        u64 m = bbit - 1ull;       // ~0 kept, 0 suppressed
                        dec |= colb[t] & m;
                        sup |= rowb[t] & m;
                        kw  |= m & (1ull << tt);
                    }
                }
                mykw |= (lane == c) ? (kw << sh) : 0ull;
                if (pf) {
                    u64* dst = kdb + (size_t)((rb + 1) & 1) * 1024;
                    for (int q = 0; q < nw; ++q) dst[q * 64 + lane] = pre[q];
                }
            }
            keepw[lane] = mykw;
        }
    } else {
        // slow path: counting rank + decode + scatter to global sorted arrays
        for (int t = tid; t < M; t += 256) {
            u64 key = skeys[t];
            int r = 0;
            for (int q = 0; q < M; ++q) r += (skeys[q] > key) ? 1 : 0;
            int n = NB - 1 - (int)(key & 0xFFFFFFFFull);
            float X1, Y1, X2, Y2;
            decode_box(x, n, X1, Y1, X2, Y2);
            gss[r] = __uint_as_float((unsigned)(key >> 32));
            gx1[r] = X1; gy1[r] = Y1; gx2[r] = X2; gy2[r] = Y2;
        }
        __threadfence_block();
        __syncthreads();
        if (tid < 64) {                           // single-wave on-the-fly sweep
            u64 kbs[3] = {0ull, 0ull, 0ull};
            for (int i = 0; i < M; ++i) {
                float ix1 = gx1[i], iy1 = gy1[i], ix2 = gx2[i], iy2 = gy2[i];
                float iar = __fmul_rn(__fsub_rn(ix2, ix1), __fsub_rn(iy2, iy1));
                int hit = 0;
                int nk = (i > lane) ? ((i - lane + 63) >> 6) : 0;
                for (int w = 0; w < 3 && !hit; ++w) {
                    int klim = nk - (w << 6);
                    if (klim <= 0) break;
                    u64 bits = kbs[w];
                    if (klim < 64) bits &= ((1ull << klim) - 1ull);
                    while (bits) {
                        int kk2 = __builtin_ctzll(bits);
                        bits &= bits - 1ull;
                        int jj = lane + (((w << 6) + kk2) << 6);
                        float jx1 = gx1[jj], jy1 = gy1[jj], jx2 = gx2[jj], jy2 = gy2[jj];
                        float jar = __fmul_rn(__fsub_rn(jx2, jx1), __fsub_rn(jy2, jy1));
                        if (iou_hit_div(ix1, iy1, ix2, iy2, iar, jx1, jy1, jx2, jy2, jar)) { hit = 1; break; }
                    }
                }
                int suppressed = __any(hit);
                if (!suppressed && lane == (i & 63)) kbs[(i >> 6) >> 6] |= 1ull << ((i >> 6) & 63);
            }
            int NWrd = (M + 63) >> 6;             // transpose to keep words
            for (int wd = 0; wd < NWrd; ++wd) {
                u64 bit = (kbs[wd >> 6] >> (wd & 63)) & 1ull;
                u64 word = __ballot(bit != 0);
                if (lane == 0 && wd < NCH) keepw[wd] = word;
            }
        }
    }
    __syncthreads();

    // emit ALL rows (zeros for non-kept)
    for (int i = tid; i < NB; i += 256) {
        bool kept = (i < M) && ((keepw[i >> 6] >> (i & 63)) & 1ull);
        if (kept) {
            float a = gx1[i], b2 = gy1[i], c2 = gx2[i], d = gy2[i];
            out[i * 5 + 0] = gss[i];
            out[i * 5 + 1] = a;
            out[i * 5 + 2] = b2;
            out[i * 5 + 3] = __fsub_rn(c2, a);
            out[i * 5 + 4] = __fsub_rn(d, b2);
            out[5 * NB + i] = 1.0f;
        } else {
            out[i * 5 + 0] = 0.0f; out[i * 5 + 1] = 0.0f; out[i * 5 + 2] = 0.0f;
            out[i * 5 + 3] = 0.0f; out[i * 5 + 4] = 0.0f;
            out[5 * NB + i] = 0.0f;
        }
    }
}

extern "C" void kernel_launch(void* const* d_in, const int* in_sizes, int n_in,
                              void* d_out, int out_size, void* d_ws, size_t ws_size,
                              hipStream_t stream) {
    const float* x = (const float*)d_in[0];
    float* out = (float*)d_out;

    // Workspace: counter | sorted f32[NB]x5 | skeys u64[NB] | adj
    char* ws = (char*)d_ws;
    int* counter = (int*)ws;                                   // 16 B
    float* fb  = (float*)(ws + 16);
    float* gss = fb + 0 * NB;
    float* gx1 = fb + 1 * NB;
    float* gy1 = fb + 2 * NB;
    float* gx2 = fb + 3 * NB;
    float* gy2 = fb + 4 * NB;
    u64* skeys = (u64*)(ws + 16 + (size_t)5 * NB * 4);         // 184,336
    size_t adj_off = 16 + (size_t)5 * NB * 4 + (size_t)NB * 8; // 258,064 B
    u64* adj = (u64*)(ws + adj_off);
    long long cap_words = (ws_size > adj_off) ? (long long)((ws_size - adj_off) / 8) : 0;

    k_prepadj<<<NPROD, 256, 0, stream>>>(x, gss, gx1, gy1, gx2, gy2,
                                         skeys, counter, adj, cap_words);
    k_sweep<<<1, 256, 0, stream>>>(x, out, gss, gx1, gy1, gx2, gy2,
                                   skeys, counter, adj, cap_words);
}

// Round 8
// 149.273 us; speedup vs baseline: 1.7082x; 1.5351x over previous
//
#include <hip/hip_runtime.h>

#define PP 96
#define NB (PP*PP)            // 9216
#define NCH (NB/64)           // 144 64-chunks
#define PROB_THR 0.9f
#define SORT_CAP 2048         // fast path capacity (W <= 32)
#define NPROD 64              // producer blocks, 32 rows each = 2048
#define PTHR 512              // k_prepadj threads (8 waves)

typedef unsigned long long u64;

// Bit-identical decode (no FMA contraction; rintf == round-half-even == jnp.round).
__device__ __forceinline__ void decode_box(const float* __restrict__ x, int n,
                                           float& X1, float& Y1, float& X2, float& Y2)
{
    float xv = x[NB + n];
    float yv = x[2 * NB + n];
    float wv = x[3 * NB + n];
    float hv = x[4 * NB + n];
    int i = n / PP;
    int j = n - i * PP;
    float bx = __fadd_rn(__fmul_rn(xv, 16.0f), (float)i * 16.0f);
    float by = __fadd_rn(__fmul_rn(yv, 16.0f), (float)j * 16.0f);
    float bw = __fmul_rn(wv, 1536.0f);
    float bh = __fmul_rn(hv, 1536.0f);
    X1 = rintf(bx);
    Y1 = rintf(by);
    X2 = rintf(__fadd_rn(bw, bx));
    Y2 = rintf(__fadd_rn(bh, by));
}

// Exact-equivalent IoU>0.5 without division (R5/R6-validated): all quantities
// are exact integers in f32 (coords <= 3072, union < 2^23);
// fl(inter/uni) > 0.5 <=> inter+inter > uni (margin 1/(2u) > 2^-24 > ulp/2).
__device__ __forceinline__ int iou_hit_nodiv(float ix1, float iy1, float ix2, float iy2, float iar,
                                             float jx1, float jy1, float jx2, float jy2, float jar)
{
    float xx1 = fmaxf(ix1, jx1), yy1 = fmaxf(iy1, jy1);
    float xx2 = fminf(ix2, jx2), yy2 = fminf(iy2, jy2);
    float iw = fmaxf(__fsub_rn(xx2, xx1), 0.0f);
    float ih = fmaxf(__fsub_rn(yy2, yy1), 0.0f);
    float inter = __fmul_rn(iw, ih);
    float uni = __fsub_rn(__fadd_rn(iar, jar), inter);
    return (uni > 0.0f && __fadd_rn(inter, inter) > uni) ? 1 : 0;
}

__device__ __forceinline__ int iou_hit_div(float ix1, float iy1, float ix2, float iy2, float iar,
                                           float jx1, float jy1, float jx2, float jy2, float jar)
{
    float xx1 = fmaxf(ix1, jx1), yy1 = fmaxf(iy1, jy1);
    float xx2 = fminf(ix2, jx2), yy2 = fminf(iy2, jy2);
    float iw = fmaxf(__fsub_rn(xx2, xx1), 0.0f);
    float ih = fmaxf(__fsub_rn(yy2, yy1), 0.0f);
    float inter = __fmul_rn(iw, ih);
    float uni = __fsub_rn(__fadd_rn(iar, jar), inter);
    return (uni > 0.0f && __fdiv_rn(inter, uni) > 0.5f) ? 1 : 0;
}

// ---------------------------------------------------------------------------
// Dispatch 1: 64 blocks x 512. Active block b (rows b*32.. < M): masks ->
// compact keys -> bitonic sort -> decode into LDS -> write its 32 adjacency
// rows (plain stores; dispatch boundary publishes). Block 0 also writes M +
// sorted arrays (fast) or compacted keys (slow path).
// ---------------------------------------------------------------------------
__global__ void __launch_bounds__(PTHR) k_prepadj(
    const float* __restrict__ x,
    float* __restrict__ gss,
    float* __restrict__ gx1, float* __restrict__ gy1,
    float* __restrict__ gx2, float* __restrict__ gy2,
    u64* __restrict__ skeys, int* __restrict__ counter,
    u64* __restrict__ adj, long long cap_words)
{
    __shared__ u64 lmask[NCH];
    __shared__ int loff[NCH];
    __shared__ int sM;
    __shared__ u64 kdb[SORT_CAP];
    __shared__ float bx1[SORT_CAP], by1[SORT_CAP], bx2[SORT_CAP], by2[SORT_CAP], bss[SORT_CAP];

    const int tid = threadIdx.x;
    const int lane = tid & 63;
    const int wv = tid >> 6;             // 8 waves
    const int b = blockIdx.x;

    for (int c = wv; c < NCH; c += 8) {
        float s = x[(c << 6) + lane];
        u64 m = __ballot(s > PROB_THR);
        if (lane == 0) lmask[c] = m;
    }
    __syncthreads();
    if (tid < NCH) {
        int off = 0;
        for (int q = 0; q < tid; ++q) off += __popcll(lmask[q]);
        loff[tid] = off;
        if (tid == NCH - 1) sM = off + __popcll(lmask[NCH - 1]);
    }
    __syncthreads();
    const int M = sM;
    const int W = (M + 63) >> 6;
    const long long R = (long long)(((M + 31) >> 5) << 5);
    const bool fast = (M <= SORT_CAP) && (R * W + 1024 <= cap_words);

    if (b == 0 && tid == 0) counter[0] = M;

    if (!fast) {
        if (b == 0) {        // publish compacted (unordered) keys for slow path
            for (int c = wv; c < NCH; c += 8) {
                float s = x[(c << 6) + lane];
                u64 m = lmask[c];
                if ((m >> lane) & 1ull) {
                    int pos = loff[c] + __popcll(m & ((1ull << lane) - 1ull));
                    int n = (c << 6) + lane;
                    skeys[pos] = ((u64)__float_as_uint(s) << 32) | (u64)(NB - 1 - n);
                }
            }
        }
        return;
    }
    if ((b << 5) >= M) return;           // block-uniform

    // compact keys into LDS (key = score-bits<<32 | NB-1-n : unique total order)
    for (int c = wv; c < NCH; c += 8) {
        float s = x[(c << 6) + lane];
        u64 m = lmask[c];
        if ((m >> lane) & 1ull) {
            int pos = loff[c] + __popcll(m & ((1ull << lane) - 1ull));
            int n = (c << 6) + lane;
            kdb[pos] = ((u64)__float_as_uint(s) << 32) | (u64)(NB - 1 - n);
        }
    }
    int S = 64; while (S < M) S <<= 1;   // pow2 sort size
    for (int q = M + tid; q < S; q += PTHR) kdb[q] = 0ull;
    __syncthreads();
    for (int k = 2; k <= S; k <<= 1) {   // bitonic, descending
        for (int j = k >> 1; j > 0; j >>= 1) {
            for (int p = tid; p < S; p += PTHR) {
                int q2 = p ^ j;
                if (q2 > p) {
                    u64 a = kdb[p], c2 = kdb[q2];
                    if ((a < c2) == ((p & k) == 0)) { kdb[p] = c2; kdb[q2] = a; }
                }
            }
            __syncthreads();
        }
    }
    for (int r = tid; r < M; r += PTHR) {
        u64 key = kdb[r];
        int n = NB - 1 - (int)(key & 0xFFFFFFFFull);
        float X1, Y1, X2, Y2;
        decode_box(x, n, X1, Y1, X2, Y2);
        bx1[r] = X1; by1[r] = Y1; bx2[r] = X2; by2[r] = Y2;
        bss[r] = __uint_as_float((unsigned)(key >> 32));
    }
    __syncthreads();

    if (b == 0) {                        // publish sorted arrays for k_sweep
        for (int r = tid; r < M; r += PTHR) {
            gss[r] = bss[r];
            gx1[r] = bx1[r]; gy1[r] = by1[r];
            gx2[r] = bx2[r]; gy2[r] = by2[r];
        }
    }

    // 32 adjacency rows owned by this block: 8 waves x 4 rows
    for (int ri = 0; ri < 4; ++ri) {
        int i = (b << 5) + (ri << 3) + wv;
        if (i >= M) break;
        float ix1 = bx1[i], iy1 = by1[i], ix2 = bx2[i], iy2 = by2[i];
        float iar = __fmul_rn(__fsub_rn(ix2, ix1), __fsub_rn(iy2, iy1));
        for (int kk = 0; kk < W; ++kk) {
            int j = (kk << 6) + lane;
            float jx1 = bx1[j], jy1 = by1[j], jx2 = bx2[j], jy2 = by2[j];
            float jar = __fmul_rn(__fsub_rn(jx2, jx1), __fsub_rn(jy2, jy1));
            int hit = (j < M) && iou_hit_nodiv(ix1, iy1, ix2, iy2, iar,
                                               jx1, jy1, jx2, jy2, jar);
            u64 mm = __ballot(hit);
            if (lane == 0) adj[(size_t)i * W + kk] = mm;
        }
    }
}

// ---------------------------------------------------------------------------
// Dispatch 2: 1 block x 256. Fast: wave 0 runs the LDS double-buffered
// register sweep over adj. ALL local-array loops have COMPILE-TIME trip
// counts (16) with uniform predication so pre[]/colb[]/rowb[] live in VGPRs
// (R6's dynamic-trip loops forced them to scratch -> 121 us). Over-reads are
// in-bounds via the R*W+1024 cap gate and masked out of consumption.
// ---------------------------------------------------------------------------
__global__ void __launch_bounds__(256) k_sweep(
    const float* __restrict__ x, float* __restrict__ out,
    float* __restrict__ gss,
    float* __restrict__ gx1, float* __restrict__ gy1,
    float* __restrict__ gx2, float* __restrict__ gy2,
    const u64* __restrict__ skeys, const int* __restrict__ counter,
    const u64* __restrict__ adj, long long cap_words)
{
    __shared__ u64 kdb[SORT_CAP];         // 16 KB sweep double-buffer
    __shared__ u64 keepw[NCH];
    int M = counter[0]; if (M > NB) M = NB;
    const int W = (M + 63) >> 6;
    const long long R = (long long)(((M + 31) >> 5) << 5);
    const bool fast = (M <= SORT_CAP) && (R * W + 1024 <= cap_words);
    const int tid = threadIdx.x, lane = tid & 63;

    if (fast) {
        if (tid < 64) {
            int wl = (lane < W) ? lane : 0;
            u64 sup = 0ull, dec = 0ull, mykw = 0ull;
            const int nrb = (M + 31) >> 5;
            const int nw = (32 * W + 63) >> 6;     // <= 16 words/lane per batch
            u64 pre[16];
            if (nrb > 0) {                          // prologue: stage block 0
                #pragma unroll
                for (int q = 0; q < 16; ++q)
                    pre[q] = (q < nw) ? adj[q * 64 + lane] : 0ull;
                #pragma unroll
                for (int q = 0; q < 16; ++q)
                    if (q < nw) kdb[q * 64 + lane] = pre[q];
            }
            for (int rb = 0; rb < nrb; ++rb) {
                int c = rb >> 1;
                u64* bp = kdb + (size_t)(rb & 1) * 1024;
                bool pf = (rb + 1 < nrb);
                if (pf) {                           // batched register prefetch
                    size_t boff = (size_t)(rb + 1) * 32 * W;
                    #pragma unroll
                    for (int q = 0; q < 16; ++q)
                        if (q < nw) pre[q] = adj[boff + q * 64 + lane];
                }
                if (!(rb & 1)) dec = (rb == 0) ? 0ull : (u64)__shfl((unsigned long long)sup, c);
                int rem = M - (c << 6);
                if (rem < 64) dec |= (~0ull) << rem;
                int sh = (rb & 1) << 5;
                u64 kw = 0ull;
                #pragma unroll
                for (int sc = 0; sc < 4; ++sc) {
                    u64 colb[8], rowb[8];
                    #pragma unroll
                    for (int t = 0; t < 8; ++t) {
                        int row = sc * 8 + t;
                        colb[t] = bp[row * W + c];
                        rowb[t] = bp[row * W + wl];
                    }
                    #pragma unroll
                    for (int t = 0; t < 8; ++t) {
                        int tt = sc * 8 + t;
                        u64 bbit = (dec >> (tt + sh)) & 1ull;
                        u64 m = bbit - 1ull;        // ~0 kept, 0 suppressed
                        dec |= colb[t] & m;
                        sup |= rowb[t] & m;
                        kw  |= m & (1ull << tt);
                    }
                }
                mykw |= (lane == c) ? (kw << sh) : 0ull;
                if (pf) {
                    u64* dst = kdb + (size_t)((rb + 1) & 1) * 1024;
                    #pragma unroll
                    for (int q = 0; q < 16; ++q)
                        if (q < nw) dst[q * 64 + lane] = pre[q];
                }
            }
            keepw[lane] = mykw;
        }
    } else {
        // slow path: counting rank + decode + scatter, then on-the-fly sweep
        for (int t = tid; t < M; t += 256) {
            u64 key = skeys[t];
            int r = 0;
            for (int q = 0; q < M; ++q) r += (skeys[q] > key) ? 1 : 0;
            int n = NB - 1 - (int)(key & 0xFFFFFFFFull);
            float X1, Y1, X2, Y2;
            decode_box(x, n, X1, Y1, X2, Y2);
            gss[r] = __uint_as_float((unsigned)(key >> 32));
            gx1[r] = X1; gy1[r] = Y1; gx2[r] = X2; gy2[r] = Y2;
        }
        __threadfence_block();
        __syncthreads();
        if (tid < 64) {
            u64 kbs[3] = {0ull, 0ull, 0ull};
            for (int i = 0; i < M; ++i) {
                float ix1 = gx1[i], iy1 = gy1[i], ix2 = gx2[i], iy2 = gy2[i];
                float iar = __fmul_rn(__fsub_rn(ix2, ix1), __fsub_rn(iy2, iy1));
                int hit = 0;
                int nk = (i > lane) ? ((i - lane + 63) >> 6) : 0;
                for (int w = 0; w < 3 && !hit; ++w) {
                    int klim = nk - (w << 6);
                    if (klim <= 0) break;
                    u64 bits = kbs[w];
                    if (klim < 64) bits &= ((1ull << klim) - 1ull);
                    while (bits) {
                        int kk2 = __builtin_ctzll(bits);
                        bits &= bits - 1ull;
                        int jj = lane + (((w << 6) + kk2) << 6);
                        float jx1 = gx1[jj], jy1 = gy1[jj], jx2 = gx2[jj], jy2 = gy2[jj];
                        float jar = __fmul_rn(__fsub_rn(jx2, jx1), __fsub_rn(jy2, jy1));
                        if (iou_hit_div(ix1, iy1, ix2, iy2, iar, jx1, jy1, jx2, jy2, jar)) { hit = 1; break; }
                    }
                }
                int suppressed = __any(hit);
                if (!suppressed && lane == (i & 63)) kbs[(i >> 6) >> 6] |= 1ull << ((i >> 6) & 63);
            }
            int NWrd = (M + 63) >> 6;
            for (int wd = 0; wd < NWrd; ++wd) {
                u64 bit = (kbs[wd >> 6] >> (wd & 63)) & 1ull;
                u64 word = __ballot(bit != 0);
                if (lane == 0 && wd < NCH) keepw[wd] = word;
            }
        }
    }
    __syncthreads();

    for (int i = tid; i < NB; i += 256) {
        bool kept = (i < M) && ((keepw[i >> 6] >> (i & 63)) & 1ull);
        if (kept) {
            float a = gx1[i], b2 = gy1[i], c2 = gx2[i], d = gy2[i];
            out[i * 5 + 0] = gss[i];
            out[i * 5 + 1] = a;
            out[i * 5 + 2] = b2;
            out[i * 5 + 3] = __fsub_rn(c2, a);
            out[i * 5 + 4] = __fsub_rn(d, b2);
            out[5 * NB + i] = 1.0f;
        } else {
            out[i * 5 + 0] = 0.0f; out[i * 5 + 1] = 0.0f; out[i * 5 + 2] = 0.0f;
            out[i * 5 + 3] = 0.0f; out[i * 5 + 4] = 0.0f;
            out[5 * NB + i] = 0.0f;
        }
    }
}

extern "C" void kernel_launch(void* const* d_in, const int* in_sizes, int n_in,
                              void* d_out, int out_size, void* d_ws, size_t ws_size,
                              hipStream_t stream) {
    const float* x = (const float*)d_in[0];
    float* out = (float*)d_out;

    char* ws = (char*)d_ws;
    int* counter = (int*)ws;                                   // 16 B
    float* fb  = (float*)(ws + 16);
    float* gss = fb + 0 * NB;
    float* gx1 = fb + 1 * NB;
    float* gy1 = fb + 2 * NB;
    float* gx2 = fb + 3 * NB;
    float* gy2 = fb + 4 * NB;
    u64* skeys = (u64*)(ws + 16 + (size_t)5 * NB * 4);
    size_t adj_off = 16 + (size_t)5 * NB * 4 + (size_t)NB * 8; // 258,064 B
    u64* adj = (u64*)(ws + adj_off);
    long long cap_words = (ws_size > adj_off) ? (long long)((ws_size - adj_off) / 8) : 0;

    k_prepadj<<<NPROD, PTHR, 0, stream>>>(x, gss, gx1, gy1, gx2, gy2,
                                          skeys, counter, adj, cap_words);
    k_sweep<<<1, 256, 0, stream>>>(x, out, gss, gx1, gy1, gx2, gy2,
                                   skeys, counter, adj, cap_words);
}

// Round 9
// 126.028 us; speedup vs baseline: 2.0233x; 1.1844x over previous
//
#include <hip/hip_runtime.h>

#define PP 96
#define NB (PP*PP)            // 9216
#define NCH (NB/64)           // 144 64-chunks
#define PROB_THR 0.9f
#define FAST_CAP 1024         // fast path: M <= 1024, W <= 16
#define LSTRIDE 1034          // padded LDS row stride (u64s): even (16B align), 2-way max bank aliasing
#define NPROD 32              // producer blocks x 32 rows = 1024
#define PTHR 512

typedef unsigned long long u64;
typedef unsigned int u32;

// Bit-identical decode (no FMA contraction; rintf == round-half-even == jnp.round).
__device__ __forceinline__ void decode_box(const float* __restrict__ x, int n,
                                           float& X1, float& Y1, float& X2, float& Y2)
{
    float xv = x[NB + n];
    float yv = x[2 * NB + n];
    float wv = x[3 * NB + n];
    float hv = x[4 * NB + n];
    int i = n / PP;
    int j = n - i * PP;
    float bx = __fadd_rn(__fmul_rn(xv, 16.0f), (float)i * 16.0f);
    float by = __fadd_rn(__fmul_rn(yv, 16.0f), (float)j * 16.0f);
    float bw = __fmul_rn(wv, 1536.0f);
    float bh = __fmul_rn(hv, 1536.0f);
    X1 = rintf(bx);
    Y1 = rintf(by);
    X2 = rintf(__fadd_rn(bw, bx));
    Y2 = rintf(__fadd_rn(bh, by));
}

// Exact-equivalent IoU>0.5 without division (R5-R7 validated).
__device__ __forceinline__ int iou_hit_nodiv(float ix1, float iy1, float ix2, float iy2, float iar,
                                             float jx1, float jy1, float jx2, float jy2, float jar)
{
    float xx1 = fmaxf(ix1, jx1), yy1 = fmaxf(iy1, jy1);
    float xx2 = fminf(ix2, jx2), yy2 = fminf(iy2, jy2);
    float iw = fmaxf(__fsub_rn(xx2, xx1), 0.0f);
    float ih = fmaxf(__fsub_rn(yy2, yy1), 0.0f);
    float inter = __fmul_rn(iw, ih);
    float uni = __fsub_rn(__fadd_rn(iar, jar), inter);
    return (uni > 0.0f && __fadd_rn(inter, inter) > uni) ? 1 : 0;
}

__device__ __forceinline__ int iou_hit_div(float ix1, float iy1, float ix2, float iy2, float iar,
                                           float jx1, float jy1, float jx2, float jy2, float jar)
{
    float xx1 = fmaxf(ix1, jx1), yy1 = fmaxf(iy1, jy1);
    float xx2 = fminf(ix2, jx2), yy2 = fminf(iy2, jy2);
    float iw = fmaxf(__fsub_rn(xx2, xx1), 0.0f);
    float ih = fmaxf(__fsub_rn(yy2, yy1), 0.0f);
    float inter = __fmul_rn(iw, ih);
    float uni = __fsub_rn(__fadd_rn(iar, jar), inter);
    return (uni > 0.0f && __fdiv_rn(inter, uni) > 0.5f) ? 1 : 0;
}

// ---------------------------------------------------------------------------
// Dispatch 1: 32 blocks x 512. Every block: zero-fill its out slice. Active
// block b: masks -> shfl-scan prefix -> compact -> bitonic sort -> decode ->
// write its 32 adjacency rows TRANSPOSED: adjT[word][row]. Block 0 publishes
// M + sorted arrays (fast) or compacted keys (slow path).
// ---------------------------------------------------------------------------
__global__ void __launch_bounds__(PTHR) k_prepadj(
    const float* __restrict__ x, float* __restrict__ out,
    float* __restrict__ gss,
    float* __restrict__ gx1, float* __restrict__ gy1,
    float* __restrict__ gx2, float* __restrict__ gy2,
    u64* __restrict__ skeys, int* __restrict__ counter,
    u64* __restrict__ adjT, long long cap_words)
{
    __shared__ u64 lmask[NCH];
    __shared__ int pc[NCH], loff[NCH];
    __shared__ int sM;
    __shared__ u64 kdb[FAST_CAP];
    __shared__ float bx1[FAST_CAP], by1[FAST_CAP], bx2[FAST_CAP], by2[FAST_CAP], bss[FAST_CAP];

    const int tid = threadIdx.x;
    const int lane = tid & 63;
    const int wv = tid >> 6;             // 8 waves
    const int b = blockIdx.x;

    // zero-fill out slice: 13824 float4 total / 32 blocks = 432 per block
    for (int q = tid; q < 432; q += PTHR)
        ((float4*)out)[b * 432 + q] = make_float4(0.f, 0.f, 0.f, 0.f);

    // validity masks
    for (int c = wv; c < NCH; c += 8) {
        float s = x[(c << 6) + lane];
        u64 m = __ballot(s > PROB_THR);
        if (lane == 0) lmask[c] = m;
    }
    __syncthreads();
    if (tid < NCH) pc[tid] = __popcll(lmask[tid]);
    __syncthreads();
    if (tid < 64) {                      // wave-parallel prefix scan (3 segs of 64)
        int acc = 0;
        for (int seg = 0; seg < 3; ++seg) {
            int c = (seg << 6) + lane;
            int pv = (c < NCH) ? pc[c] : 0;
            int v = pv;
            #pragma unroll
            for (int off = 1; off < 64; off <<= 1) {
                int u = __shfl_up(v, off);
                if (lane >= off) v += u;
            }
            if (c < NCH) loff[c] = acc + v - pv;
            acc += __shfl(v, 63);
        }
        if (lane == 0) sM = acc;
    }
    __syncthreads();
    const int M = sM;
    const int W = (M + 63) >> 6;
    const bool fast = (M <= FAST_CAP) && (cap_words >= 16384);

    if (b == 0 && tid == 0) counter[0] = M;

    if (!fast) {
        if (b == 0) {                    // publish compacted keys for slow path
            for (int c = wv; c < NCH; c += 8) {
                float s = x[(c << 6) + lane];
                u64 m = lmask[c];
                if ((m >> lane) & 1ull) {
                    int pos = loff[c] + __popcll(m & ((1ull << lane) - 1ull));
                    int n = (c << 6) + lane;
                    skeys[pos] = ((u64)__float_as_uint(s) << 32) | (u64)(NB - 1 - n);
                }
            }
        }
        return;
    }
    if ((b << 5) >= M) return;           // block-uniform

    // compact keys into LDS (key = score-bits<<32 | NB-1-n : unique total order)
    for (int c = wv; c < NCH; c += 8) {
        float s = x[(c << 6) + lane];
        u64 m = lmask[c];
        if ((m >> lane) & 1ull) {
            int pos = loff[c] + __popcll(m & ((1ull << lane) - 1ull));
            int n = (c << 6) + lane;
            kdb[pos] = ((u64)__float_as_uint(s) << 32) | (u64)(NB - 1 - n);
        }
    }
    int S = 64; while (S < M) S <<= 1;   // pow2 sort size <= 1024
    for (int q = M + tid; q < S; q += PTHR) kdb[q] = 0ull;
    __syncthreads();
    for (int k = 2; k <= S; k <<= 1) {   // bitonic, descending (validated)
        for (int j = k >> 1; j > 0; j >>= 1) {
            for (int p = tid; p < S; p += PTHR) {
                int q2 = p ^ j;
                if (q2 > p) {
                    u64 a = kdb[p], c2 = kdb[q2];
                    if ((a < c2) == ((p & k) == 0)) { kdb[p] = c2; kdb[q2] = a; }
                }
            }
            __syncthreads();
        }
    }
    for (int r = tid; r < M; r += PTHR) {
        u64 key = kdb[r];
        int n = NB - 1 - (int)(key & 0xFFFFFFFFull);
        float X1, Y1, X2, Y2;
        decode_box(x, n, X1, Y1, X2, Y2);
        bx1[r] = X1; by1[r] = Y1; bx2[r] = X2; by2[r] = Y2;
        bss[r] = __uint_as_float((unsigned)(key >> 32));
    }
    __syncthreads();

    if (b == 0) {                        // publish sorted arrays for k_sweep
        for (int r = tid; r < M; r += PTHR) {
            gss[r] = bss[r];
            gx1[r] = bx1[r]; gy1[r] = by1[r];
            gx2[r] = bx2[r]; gy2[r] = by2[r];
        }
    }

    // 32 adjacency rows: 8 waves x 4 rows, stored transposed adjT[kk][i]
    for (int ri = 0; ri < 4; ++ri) {
        int i = (b << 5) + (ri << 3) + wv;
        if (i >= M) break;
        float ix1 = bx1[i], iy1 = by1[i], ix2 = bx2[i], iy2 = by2[i];
        float iar = __fmul_rn(__fsub_rn(ix2, ix1), __fsub_rn(iy2, iy1));
        for (int kk = 0; kk < W; ++kk) {
            int j = (kk << 6) + lane;
            float jx1 = bx1[j & (FAST_CAP-1)], jy1 = by1[j & (FAST_CAP-1)];
            float jx2 = bx2[j & (FAST_CAP-1)], jy2 = by2[j & (FAST_CAP-1)];
            float jar = __fmul_rn(__fsub_rn(jx2, jx1), __fsub_rn(jy2, jy1));
            int hit = (j < M) && iou_hit_nodiv(ix1, iy1, ix2, iy2, iar,
                                               jx1, jy1, jx2, jy2, jar);
            u64 mm = __ballot(hit);
            if (lane == 0) adjT[(size_t)kk * 1024 + i] = mm;
        }
    }
}

// One 8-row chain step set; DSRC = dl (first 32 rows of word) or dh (second).
#define SUBCHUNK(DSRC)                                                        \
    {                                                                         \
        const ulonglong2* cp2 = (const ulonglong2*)(Lds + cbase + (sc << 3)); \
        const ulonglong2* rp2 = (const ulonglong2*)(Lds + rbase + (sc << 3)); \
        ulonglong2 ca = cp2[0], cb = cp2[1], cc = cp2[2], cd = cp2[3];        \
        ulonglong2 ra = rp2[0], rbv = rp2[1], rc = rp2[2], rd = rp2[3];       \
        u64 colb[8] = {ca.x, ca.y, cb.x, cb.y, cc.x, cc.y, cd.x, cd.y};       \
        u64 rowb[8] = {ra.x, ra.y, rbv.x, rbv.y, rc.x, rc.y, rd.x, rd.y};     \
        _Pragma("unroll")                                                     \
        for (int t = 0; t < 8; ++t) {                                         \
            const int bitp = (sc << 3) + t;                                   \
            u32 bbit = ((DSRC) >> bitp) & 1u;                                 \
            u32 m = bbit - 1u;              /* ~0 kept, 0 suppressed */       \
            dl |= (u32)colb[t] & m;                                           \
            dh |= (u32)(colb[t] >> 32) & m;                                   \
            supl |= (u32)rowb[t] & m;                                         \
            suph |= (u32)(rowb[t] >> 32) & m;                                 \
            kw |= m & (1u << bitp);                                           \
        }                                                                     \
    }

// ---------------------------------------------------------------------------
// Dispatch 2: 1 block x 256. Fast: stage adjT into 132 KB LDS (coalesced
// ulonglong2), then wave 0 sweeps entirely from LDS: per 32-row block, 4
// sub-chunks of (8 x ds_read_b128 + u32-half chain). No global loads, no
// dbuf, no ds_writes in the loop. Emit kept rows only (out pre-zeroed).
// ---------------------------------------------------------------------------
__global__ void __launch_bounds__(256) k_sweep(
    const float* __restrict__ x, float* __restrict__ out,
    float* __restrict__ gss,
    float* __restrict__ gx1, float* __restrict__ gy1,
    float* __restrict__ gx2, float* __restrict__ gy2,
    const u64* __restrict__ skeys, const int* __restrict__ counter,
    const u64* __restrict__ adjT, long long cap_words)
{
    __shared__ __align__(16) u64 Lds[16 * LSTRIDE];   // 132,352 B (gfx950: 160 KB LDS)
    __shared__ u64 keepw[NCH];
    int M = counter[0]; if (M > NB) M = NB;
    const int W = (M + 63) >> 6;
    const bool fast = (M <= FAST_CAP) && (cap_words >= 16384);
    const int tid = threadIdx.x, lane = tid & 63;

    if (fast) {
        // stage adjT[w][0..1023] -> Lds[w*LSTRIDE + i], 16B granules
        const int npair = W << 9;                     // W*512 ulonglong2
        const ulonglong2* gp = (const ulonglong2*)adjT;
        for (int f = tid; f < npair; f += 256) {
            int w = f >> 9, r2 = f & 511;
            ((ulonglong2*)Lds)[w * (LSTRIDE >> 1) + r2] = gp[f];
        }
        __syncthreads();

        if (tid < 64) {
            const int wl = (lane < W) ? lane : 0;
            u32 supl = 0u, suph = 0u, dl = 0u, dh = 0u;
            u64 mykw = 0ull;
            const int nrb = (M + 31) >> 5;
            for (int rb = 0; rb < nrb; ++rb) {
                const int c = rb >> 1;
                const int base = rb << 5;
                const size_t cbase = (size_t)c * LSTRIDE + base;
                const size_t rbase = (size_t)wl * LSTRIDE + base;
                if (!(rb & 1)) {
                    if (rb == 0) { dl = 0u; dh = 0u; }
                    else { dl = (u32)__shfl((int)supl, c); dh = (u32)__shfl((int)suph, c); }
                    int rem = M - (c << 6);           // tail: mark rows >= M suppressed
                    if (rem < 64) {
                        if (rem >= 32) dh |= 0xFFFFFFFFu << (rem - 32);
                        else { dh = 0xFFFFFFFFu; dl |= 0xFFFFFFFFu << rem; }
                    }
                }
                u32 kw = 0u;
                if (!(rb & 1)) {
                    #pragma unroll
                    for (int sc = 0; sc < 4; ++sc) SUBCHUNK(dl)
                } else {
                    #pragma unroll
                    for (int sc = 0; sc < 4; ++sc) SUBCHUNK(dh)
                }
                mykw |= (lane == c) ? ((u64)kw << ((rb & 1) << 5)) : 0ull;
            }
            keepw[lane] = mykw;
        }
    } else {
        // slow path (M > 1024; never hit for this distribution): counting rank
        // + decode + single-wave on-the-fly sweep (R1/R7-validated).
        for (int t = tid; t < M; t += 256) {
            u64 key = skeys[t];
            int r = 0;
            for (int q = 0; q < M; ++q) r += (skeys[q] > key) ? 1 : 0;
            int n = NB - 1 - (int)(key & 0xFFFFFFFFull);
            float X1, Y1, X2, Y2;
            decode_box(x, n, X1, Y1, X2, Y2);
            gss[r] = __uint_as_float((unsigned)(key >> 32));
            gx1[r] = X1; gy1[r] = Y1; gx2[r] = X2; gy2[r] = Y2;
        }
        __threadfence_block();
        __syncthreads();
        if (tid < 64) {
            u64 kbs[3] = {0ull, 0ull, 0ull};
            for (int i = 0; i < M; ++i) {
                float ix1 = gx1[i], iy1 = gy1[i], ix2 = gx2[i], iy2 = gy2[i];
                float iar = __fmul_rn(__fsub_rn(ix2, ix1), __fsub_rn(iy2, iy1));
                int hit = 0;
                int nk = (i > lane) ? ((i - lane + 63) >> 6) : 0;
                for (int w = 0; w < 3 && !hit; ++w) {
                    int klim = nk - (w << 6);
                    if (klim <= 0) break;
                    u64 bits = kbs[w];
                    if (klim < 64) bits &= ((1ull << klim) - 1ull);
                    while (bits) {
                        int kk2 = __builtin_ctzll(bits);
                        bits &= bits - 1ull;
                        int jj = lane + (((w << 6) + kk2) << 6);
                        float jx1 = gx1[jj], jy1 = gy1[jj], jx2 = gx2[jj], jy2 = gy2[jj];
                        float jar = __fmul_rn(__fsub_rn(jx2, jx1), __fsub_rn(jy2, jy1));
                        if (iou_hit_div(ix1, iy1, ix2, iy2, iar, jx1, jy1, jx2, jy2, jar)) { hit = 1; break; }
                    }
                }
                int suppressed = __any(hit);
                if (!suppressed && lane == (i & 63)) kbs[(i >> 6) >> 6] |= 1ull << ((i >> 6) & 63);
            }
            int NWrd = (M + 63) >> 6;
            for (int wd = 0; wd < NWrd; ++wd) {
                u64 bit = (kbs[wd >> 6] >> (wd & 63)) & 1ull;
                u64 word = __ballot(bit != 0);
                if (lane == 0 && wd < NCH) keepw[wd] = word;
            }
        }
    }
    __syncthreads();

    // emit kept rows only (non-kept rows pre-zeroed by k_prepadj)
    for (int i = tid; i < M; i += 256) {
        if ((keepw[i >> 6] >> (i & 63)) & 1ull) {
            float a = gx1[i], b2 = gy1[i], c2 = gx2[i], d = gy2[i];
            out[i * 5 + 0] = gss[i];
            out[i * 5 + 1] = a;
            out[i * 5 + 2] = b2;
            out[i * 5 + 3] = __fsub_rn(c2, a);
            out[i * 5 + 4] = __fsub_rn(d, b2);
            out[5 * NB + i] = 1.0f;
        }
    }
}

extern "C" void kernel_launch(void* const* d_in, const int* in_sizes, int n_in,
                              void* d_out, int out_size, void* d_ws, size_t ws_size,
                              hipStream_t stream) {
    const float* x = (const float*)d_in[0];
    float* out = (float*)d_out;

    // Workspace: counter 16 | sorted f32[NB]x5 | UNION{ skeys u64[NB] (slow),
    // adjT u64[16*1024] (fast) } — mutually exclusive, keeps footprint within
    // the proven >=516 KB workspace.
    char* ws = (char*)d_ws;
    int* counter = (int*)ws;
    float* fb  = (float*)(ws + 16);
    float* gss = fb + 0 * NB;
    float* gx1 = fb + 1 * NB;
    float* gy1 = fb + 2 * NB;
    float* gx2 = fb + 3 * NB;
    float* gy2 = fb + 4 * NB;
    size_t adj_off = 16 + (size_t)5 * NB * 4;          // 184,336 (16-aligned)
    u64* adjT  = (u64*)(ws + adj_off);
    u64* skeys = adjT;                                  // aliased (exclusive use)
    long long cap_words = (ws_size > adj_off) ? (long long)((ws_size - adj_off) / 8) : 0;

    k_prepadj<<<NPROD, PTHR, 0, stream>>>(x, out, gss, gx1, gy1, gx2, gy2,
                                          skeys, counter, adjT, cap_words);
    k_sweep<<<1, 256, 0, stream>>>(x, out, gss, gx1, gy1, gx2, gy2,
                                   skeys, counter, adjT, cap_words);
}

// Round 10
// 118.963 us; speedup vs baseline: 2.1434x; 1.0594x over previous
//
#include <hip/hip_runtime.h>

#define PP 96
#define NB (PP*PP)            // 9216
#define NCH (NB/64)           // 144 64-chunks
#define PROB_THR 0.9f
#define FAST_CAP 1024         // fast path: M <= 1024, W <= 16
#define LSTRIDE 1034          // padded LDS row stride (u64): even (16B), 2-way max aliasing

typedef unsigned long long u64;
typedef unsigned int u32;

// Bit-identical decode core (no FMA contraction; rintf == round-half-even).
__device__ __forceinline__ void decode_core(int n, float xv, float yv, float wv, float hv,
                                            float& X1, float& Y1, float& X2, float& Y2)
{
    int i = n / PP;
    int j = n - i * PP;
    float bx = __fadd_rn(__fmul_rn(xv, 16.0f), (float)i * 16.0f);
    float by = __fadd_rn(__fmul_rn(yv, 16.0f), (float)j * 16.0f);
    float bw = __fmul_rn(wv, 1536.0f);
    float bh = __fmul_rn(hv, 1536.0f);
    X1 = rintf(bx);
    Y1 = rintf(by);
    X2 = rintf(__fadd_rn(bw, bx));
    Y2 = rintf(__fadd_rn(bh, by));
}

__device__ __forceinline__ void decode_box(const float* __restrict__ x, int n,
                                           float& X1, float& Y1, float& X2, float& Y2)
{
    decode_core(n, x[NB + n], x[2 * NB + n], x[3 * NB + n], x[4 * NB + n], X1, Y1, X2, Y2);
}

// Exact-equivalent IoU>0.5 without division (R5-R8 validated on HW).
__device__ __forceinline__ int iou_hit_nodiv(float ix1, float iy1, float ix2, float iy2, float iar,
                                             float jx1, float jy1, float jx2, float jy2, float jar)
{
    float xx1 = fmaxf(ix1, jx1), yy1 = fmaxf(iy1, jy1);
    float xx2 = fminf(ix2, jx2), yy2 = fminf(iy2, jy2);
    float iw = fmaxf(__fsub_rn(xx2, xx1), 0.0f);
    float ih = fmaxf(__fsub_rn(yy2, yy1), 0.0f);
    float inter = __fmul_rn(iw, ih);
    float uni = __fsub_rn(__fadd_rn(iar, jar), inter);
    return (uni > 0.0f && __fadd_rn(inter, inter) > uni) ? 1 : 0;
}

__device__ __forceinline__ int iou_hit_div(float ix1, float iy1, float ix2, float iy2, float iar,
                                           float jx1, float jy1, float jx2, float jy2, float jar)
{
    float xx1 = fmaxf(ix1, jx1), yy1 = fmaxf(iy1, jy1);
    float xx2 = fminf(ix2, jx2), yy2 = fminf(iy2, jy2);
    float iw = fmaxf(__fsub_rn(xx2, xx1), 0.0f);
    float ih = fmaxf(__fsub_rn(yy2, yy1), 0.0f);
    float inter = __fmul_rn(iw, ih);
    float uni = __fsub_rn(__fadd_rn(iar, jar), inter);
    return (uni > 0.0f && __fdiv_rn(inter, uni) > 0.5f) ? 1 : 0;
}

// ---------------------------------------------------------------------------
// Dispatch 1: k_sort, 1 block x 512. Mask (6-deep batched cold loads) ->
// wave-parallel prefix -> compact keys to LDS -> counting rank (readlane
// broadcast, 2 candidates/thread, decode gathers hoisted) -> scatter sorted
// float4 boxes + scores to global. Writes M. Slow path (M>1024): publish
// compacted keys only.
// ---------------------------------------------------------------------------
__global__ void __launch_bounds__(512) k_sort(
    const float* __restrict__ x,
    float* __restrict__ gss, float4* __restrict__ gbox,
    u64* __restrict__ skeys, int* __restrict__ counter, int ws_ok)
{
    __shared__ u64 lmask[NCH];
    __shared__ int pc[NCH], loff[NCH];
    __shared__ int sM;
    __shared__ u64 kdb[FAST_CAP];

    const int tid = threadIdx.x;
    const int lane = tid & 63;
    const int wv = tid >> 6;                  // 8 waves; 144 = 8 * 18 chunks

    // ---- mask pass: 18 chunks/wave, batched 6 deep (3 cold latencies) ----
    #pragma unroll
    for (int g = 0; g < 18; g += 6) {
        float sv[6];
        #pragma unroll
        for (int u = 0; u < 6; ++u)
            sv[u] = x[((wv + ((g + u) << 3)) << 6) + lane];
        #pragma unroll
        for (int u = 0; u < 6; ++u) {
            u64 m = __ballot(sv[u] > PROB_THR);
            if (lane == 0) lmask[wv + ((g + u) << 3)] = m;
        }
    }
    __syncthreads();
    if (tid < NCH) pc[tid] = __popcll(lmask[tid]);
    __syncthreads();
    if (tid < 64) {                           // wave-parallel prefix (validated R8)
        int acc = 0;
        for (int seg = 0; seg < 3; ++seg) {
            int c = (seg << 6) + lane;
            int pv = (c < NCH) ? pc[c] : 0;
            int v = pv;
            #pragma unroll
            for (int off = 1; off < 64; off <<= 1) {
                int u = __shfl_up(v, off);
                if (lane >= off) v += u;
            }
            if (c < NCH) loff[c] = acc + v - pv;
            acc += __shfl(v, 63);
        }
        if (lane == 0) sM = acc;
    }
    __syncthreads();
    const int M = sM;
    const bool fast = (M <= FAST_CAP) && ws_ok;
    if (tid == 0) counter[0] = M;

    if (!fast) {                              // publish compacted keys for slow path
        for (int c = wv; c < NCH; c += 8) {
            float s = x[(c << 6) + lane];
            u64 m = lmask[c];
            if ((m >> lane) & 1ull) {
                int pos = loff[c] + __popcll(m & ((1ull << lane) - 1ull));
                int n = (c << 6) + lane;
                skeys[pos] = ((u64)__float_as_uint(s) << 32) | (u64)(NB - 1 - n);
            }
        }
        return;
    }

    // ---- compact keys into LDS (key = score-bits<<32 | NB-1-n : unique) ----
    for (int c = wv; c < NCH; c += 8) {
        float s = x[(c << 6) + lane];          // L1-warm
        u64 m = lmask[c];
        if ((m >> lane) & 1ull) {
            int pos = loff[c] + __popcll(m & ((1ull << lane) - 1ull));
            int n = (c << 6) + lane;
            kdb[pos] = ((u64)__float_as_uint(s) << 32) | (u64)(NB - 1 - n);
        }
    }
    for (int q = M + tid; q < FAST_CAP; q += 512) kdb[q] = 0ull;  // pad (< any valid key)
    __syncthreads();

    // ---- counting rank: 2 candidates/thread; decode gathers hoisted ----
    u64 k0 = kdb[tid], k1 = kdb[tid + 512];
    int n0 = NB - 1 - (int)(k0 & 0xFFFFFFFFull);    // pad -> n = NB-1 (valid addr)
    int n1 = NB - 1 - (int)(k1 & 0xFFFFFFFFull);
    float xv0 = x[NB + n0], yv0 = x[2 * NB + n0], wv0 = x[3 * NB + n0], hv0 = x[4 * NB + n0];
    float xv1 = x[NB + n1], yv1 = x[2 * NB + n1], wv1 = x[3 * NB + n1], hv1 = x[4 * NB + n1];
    int r0 = 0, r1 = 0;
    const int nck = (M + 63) >> 6;
    for (int ch = 0; ch < nck; ++ch) {
        u64 kq = kdb[(ch << 6) + lane];        // lane l holds key[ch*64+l]
        u32 qlo = (u32)kq, qhi = (u32)(kq >> 32);
        #pragma unroll
        for (int i = 0; i < 64; ++i) {         // broadcast via readlane (SGPR), no LDS
            u32 blo = (u32)__builtin_amdgcn_readlane((int)qlo, i);
            u32 bhi = (u32)__builtin_amdgcn_readlane((int)qhi, i);
            u64 kb = ((u64)bhi << 32) | (u64)blo;
            r0 += (kb > k0) ? 1 : 0;
            r1 += (kb > k1) ? 1 : 0;
        }
    }
    if (tid < M) {
        float X1, Y1, X2, Y2;
        decode_core(n0, xv0, yv0, wv0, hv0, X1, Y1, X2, Y2);
        gbox[r0] = make_float4(X1, Y1, X2, Y2);
        gss[r0] = __uint_as_float((u32)(k0 >> 32));
    }
    if (tid + 512 < M) {
        float X1, Y1, X2, Y2;
        decode_core(n1, xv1, yv1, wv1, hv1, X1, Y1, X2, Y2);
        gbox[r1] = make_float4(X1, Y1, X2, Y2);
        gss[r1] = __uint_as_float((u32)(k1 >> 32));
    }
}

// ---------------------------------------------------------------------------
// Dispatch 2: k_adj, 64 blocks x 256. Zero-fill out slice (always). Fast:
// stage sorted float4 boxes + areas into LDS (coalesced b128), build 16
// adjacency rows/block (b128 box reads), write adjT[word][row].
// ---------------------------------------------------------------------------
__global__ void __launch_bounds__(256) k_adj(
    float* __restrict__ out, const float4* __restrict__ gbox,
    const int* __restrict__ counter, u64* __restrict__ adjT, int ws_ok)
{
    __shared__ float4 lb[FAST_CAP];           // 16 KB
    __shared__ float la[FAST_CAP];            // 4 KB
    int M = counter[0]; if (M > NB) M = NB;
    const int tid = threadIdx.x, lane = tid & 63, wv = tid >> 6, b = blockIdx.x;

    // zero-fill out: 13824 float4 / 64 blocks = 216 each
    float4 z4 = make_float4(0.f, 0.f, 0.f, 0.f);
    for (int q = tid; q < 216; q += 256)
        ((float4*)out)[b * 216 + q] = z4;

    const bool fast = (M <= FAST_CAP) && ws_ok;
    if (!fast) return;
    if ((b << 4) >= M) return;                // block-uniform

    const int W = (M + 63) >> 6;
    for (int f = tid; f < M; f += 256) {
        float4 bb = gbox[f];
        lb[f] = bb;
        la[f] = __fmul_rn(__fsub_rn(bb.z, bb.x), __fsub_rn(bb.w, bb.y));
    }
    __syncthreads();

    #pragma unroll
    for (int r = 0; r < 4; ++r) {             // 16 rows/block: 4 waves x 4 rows
        int i = (b << 4) + (r << 2) + wv;
        if (i >= M) break;
        float4 bi = lb[i];
        float iar = la[i];
        for (int kk = 0; kk < W; ++kk) {
            int j = (kk << 6) + lane;
            float4 bj = lb[j & (FAST_CAP - 1)];
            float jar = la[j & (FAST_CAP - 1)];
            int hit = (j < M) && iou_hit_nodiv(bi.x, bi.y, bi.z, bi.w, iar,
                                               bj.x, bj.y, bj.z, bj.w, jar);
            u64 mm = __ballot(hit);
            if (lane == 0) adjT[((size_t)kk << 10) + i] = mm;
        }
    }
}

// One 8-row chain step set; DSRC = dl (first 32 rows of word) or dh (second).
#define SUBCHUNK(DSRC)                                                        \
    {                                                                         \
        const ulonglong2* cp2 = (const ulonglong2*)(Lds + cbase + (sc << 3)); \
        const ulonglong2* rp2 = (const ulonglong2*)(Lds + rbase + (sc << 3)); \
        ulonglong2 ca = cp2[0], cb = cp2[1], cc = cp2[2], cd = cp2[3];        \
        ulonglong2 ra = rp2[0], rbv = rp2[1], rc = rp2[2], rd = rp2[3];       \
        u64 colb[8] = {ca.x, ca.y, cb.x, cb.y, cc.x, cc.y, cd.x, cd.y};       \
        u64 rowb[8] = {ra.x, ra.y, rbv.x, rbv.y, rc.x, rc.y, rd.x, rd.y};     \
        _Pragma("unroll")                                                     \
        for (int t = 0; t < 8; ++t) {                                         \
            const int bitp = (sc << 3) + t;                                   \
            u32 bbit = ((DSRC) >> bitp) & 1u;                                 \
            u32 m = bbit - 1u;              /* ~0 kept, 0 suppressed */       \
            dl |= (u32)colb[t] & m;                                           \
            dh |= (u32)(colb[t] >> 32) & m;                                   \
            supl |= (u32)rowb[t] & m;                                         \
            suph |= (u32)(rowb[t] >> 32) & m;                                 \
            kw |= m & (1u << bitp);                                           \
        }                                                                     \
    }

// ---------------------------------------------------------------------------
// Dispatch 3: k_sweep, 1 block x 256 (R8-validated LDS sweep; staging
// unrolled 8-deep so 32 load rounds -> 4 vmcnt waits). Emit kept rows only
// (out pre-zeroed by k_adj). Slow fallback for M > 1024.
// ---------------------------------------------------------------------------
__global__ void __launch_bounds__(256) k_sweep(
    const float* __restrict__ x, float* __restrict__ out,
    float* __restrict__ gss, float4* __restrict__ gbox,
    const u64* __restrict__ skeys, const int* __restrict__ counter,
    const u64* __restrict__ adjT, int ws_ok)
{
    __shared__ __align__(16) u64 Lds[16 * LSTRIDE];   // 132,352 B
    __shared__ u64 keepw[NCH];
    int M = counter[0]; if (M > NB) M = NB;
    const int W = (M + 63) >> 6;
    const bool fast = (M <= FAST_CAP) && ws_ok;
    const int tid = threadIdx.x, lane = tid & 63;

    if (fast) {
        // ---- stage adjT -> LDS, 8-deep batched 16B loads ----
        const int npair = W << 9;                     // W*512 ulonglong2
        const ulonglong2* gp = (const ulonglong2*)adjT;
        for (int r = 0; r < 4; ++r) {
            int fb = (r << 11) + tid;                 // r*2048 + tid
            ulonglong2 v[8];
            #pragma unroll
            for (int u = 0; u < 8; ++u) {
                int f = fb + (u << 8);
                v[u] = (f < npair) ? gp[f] : make_ulonglong2(0ull, 0ull);
            }
            #pragma unroll
            for (int u = 0; u < 8; ++u) {
                int f = fb + (u << 8);
                if (f < npair) {
                    int w = f >> 9, r2 = f & 511;
                    ((ulonglong2*)Lds)[w * (LSTRIDE >> 1) + r2] = v[u];
                }
            }
        }
        __syncthreads();

        if (tid < 64) {
            const int wl = (lane < W) ? lane : 0;
            u32 supl = 0u, suph = 0u, dl = 0u, dh = 0u;
            u64 mykw = 0ull;
            const int nrb = (M + 31) >> 5;
            for (int rb = 0; rb < nrb; ++rb) {
                const int c = rb >> 1;
                const int base = rb << 5;
                const size_t cbase = (size_t)c * LSTRIDE + base;
                const size_t rbase = (size_t)wl * LSTRIDE + base;
                if (!(rb & 1)) {
                    if (rb == 0) { dl = 0u; dh = 0u; }
                    else { dl = (u32)__shfl((int)supl, c); dh = (u32)__shfl((int)suph, c); }
                    int rem = M - (c << 6);           // tail: rows >= M suppressed
                    if (rem < 64) {
                        if (rem >= 32) dh |= 0xFFFFFFFFu << (rem - 32);
                        else { dh = 0xFFFFFFFFu; dl |= 0xFFFFFFFFu << rem; }
                    }
                }
                u32 kw = 0u;
                if (!(rb & 1)) {
                    #pragma unroll
                    for (int sc = 0; sc < 4; ++sc) SUBCHUNK(dl)
                } else {
                    #pragma unroll
                    for (int sc = 0; sc < 4; ++sc) SUBCHUNK(dh)
                }
                mykw |= (lane == c) ? ((u64)kw << ((rb & 1) << 5)) : 0ull;
            }
            keepw[lane] = mykw;
        }
    } else {
        // slow path (M > 1024): counting rank from skeys + decode + scatter,
        // then single-wave on-the-fly sweep (R1/R7 logic, float4 storage).
        for (int t = tid; t < M; t += 256) {
            u64 key = skeys[t];
            int r = 0;
            for (int q = 0; q < M; ++q) r += (skeys[q] > key) ? 1 : 0;
            int n = NB - 1 - (int)(key & 0xFFFFFFFFull);
            float X1, Y1, X2, Y2;
            decode_box(x, n, X1, Y1, X2, Y2);
            gbox[r] = make_float4(X1, Y1, X2, Y2);
            gss[r] = __uint_as_float((u32)(key >> 32));
        }
        __threadfence();
        __syncthreads();
        if (tid < 64) {
            u64 kbs[3] = {0ull, 0ull, 0ull};
            for (int i = 0; i < M; ++i) {
                float4 bi = gbox[i];
                float iar = __fmul_rn(__fsub_rn(bi.z, bi.x), __fsub_rn(bi.w, bi.y));
                int hit = 0;
                int nk = (i > lane) ? ((i - lane + 63) >> 6) : 0;
                for (int w = 0; w < 3 && !hit; ++w) {
                    int klim = nk - (w << 6);
                    if (klim <= 0) break;
                    u64 bits = kbs[w];
                    if (klim < 64) bits &= ((1ull << klim) - 1ull);
                    while (bits) {
                        int kk2 = __builtin_ctzll(bits);
                        bits &= bits - 1ull;
                        int jj = lane + (((w << 6) + kk2) << 6);
                        float4 bj = gbox[jj];
                        float jar = __fmul_rn(__fsub_rn(bj.z, bj.x), __fsub_rn(bj.w, bj.y));
                        if (iou_hit_div(bi.x, bi.y, bi.z, bi.w, iar,
                                        bj.x, bj.y, bj.z, bj.w, jar)) { hit = 1; break; }
                    }
                }
                int suppressed = __any(hit);
                if (!suppressed && lane == (i & 63)) kbs[(i >> 6) >> 6] |= 1ull << ((i >> 6) & 63);
            }
            int NWrd = (M + 63) >> 6;
            for (int wd = 0; wd < NWrd; ++wd) {
                u64 bit = (kbs[wd >> 6] >> (wd & 63)) & 1ull;
                u64 word = __ballot(bit != 0);
                if (lane == 0 && wd < NCH) keepw[wd] = word;
            }
        }
    }
    __syncthreads();

    // emit kept rows only (rest pre-zeroed by k_adj)
    for (int i = tid; i < M; i += 256) {
        if ((keepw[i >> 6] >> (i & 63)) & 1ull) {
            float4 bb = gbox[i];
            out[i * 5 + 0] = gss[i];
            out[i * 5 + 1] = bb.x;
            out[i * 5 + 2] = bb.y;
            out[i * 5 + 3] = __fsub_rn(bb.z, bb.x);
            out[i * 5 + 4] = __fsub_rn(bb.w, bb.y);
            out[5 * NB + i] = 1.0f;
        }
    }
}

extern "C" void kernel_launch(void* const* d_in, const int* in_sizes, int n_in,
                              void* d_out, int out_size, void* d_ws, size_t ws_size,
                              hipStream_t stream) {
    const float* x = (const float*)d_in[0];
    float* out = (float*)d_out;

    // Workspace (no aliasing; all 16B aligned):
    // counter 16 | gss f32[NB] | gbox float4[NB] | adjT u64[16*1024] | skeys u64[NB]
    char* ws = (char*)d_ws;
    int* counter = (int*)ws;
    float*  gss  = (float*)(ws + 16);
    float4* gbox = (float4*)(ws + 16 + (size_t)4 * NB);            // 36,880
    u64*    adjT = (u64*)(ws + 16 + (size_t)4 * NB + (size_t)16 * NB);  // 184,336
    u64*    skeys = (u64*)((char*)adjT + (size_t)16384 * 8);       // 315,408
    const size_t NEEDED = 16 + (size_t)4 * NB + (size_t)16 * NB
                        + (size_t)16384 * 8 + (size_t)8 * NB;      // 389,136
    int ws_ok = (ws_size >= NEEDED) ? 1 : 0;

    k_sort<<<1, 512, 0, stream>>>(x, gss, gbox, skeys, counter, ws_ok);
    k_adj<<<64, 256, 0, stream>>>(out, gbox, counter, adjT, ws_ok);
    k_sweep<<<1, 256, 0, stream>>>(x, out, gss, gbox, skeys, counter, adjT, ws_ok);
}

// Round 11
// 112.330 us; speedup vs baseline: 2.2700x; 1.0591x over previous
//
#include <hip/hip_runtime.h>

#define PP 96
#define NB (PP*PP)            // 9216
#define NCH (NB/64)           // 144 64-chunks
#define PROB_THR 0.9f
#define FAST_CAP 1024         // fast path: M <= 1024, W <= 16
#define LSTRIDE 1034          // padded LDS row stride (u64): even (16B), 2-way max aliasing

typedef unsigned long long u64;
typedef unsigned int u32;

// Bit-identical decode core (no FMA contraction; rintf == round-half-even).
__device__ __forceinline__ void decode_core(int n, float xv, float yv, float wv, float hv,
                                            float& X1, float& Y1, float& X2, float& Y2)
{
    int i = n / PP;
    int j = n - i * PP;
    float bx = __fadd_rn(__fmul_rn(xv, 16.0f), (float)i * 16.0f);
    float by = __fadd_rn(__fmul_rn(yv, 16.0f), (float)j * 16.0f);
    float bw = __fmul_rn(wv, 1536.0f);
    float bh = __fmul_rn(hv, 1536.0f);
    X1 = rintf(bx);
    Y1 = rintf(by);
    X2 = rintf(__fadd_rn(bw, bx));
    Y2 = rintf(__fadd_rn(bh, by));
}

__device__ __forceinline__ void decode_box(const float* __restrict__ x, int n,
                                           float& X1, float& Y1, float& X2, float& Y2)
{
    decode_core(n, x[NB + n], x[2 * NB + n], x[3 * NB + n], x[4 * NB + n], X1, Y1, X2, Y2);
}

// Exact-equivalent IoU>0.5 without division (R5-R9 validated on HW).
__device__ __forceinline__ int iou_hit_nodiv(float ix1, float iy1, float ix2, float iy2, float iar,
                                             float jx1, float jy1, float jx2, float jy2, float jar)
{
    float xx1 = fmaxf(ix1, jx1), yy1 = fmaxf(iy1, jy1);
    float xx2 = fminf(ix2, jx2), yy2 = fminf(iy2, jy2);
    float iw = fmaxf(__fsub_rn(xx2, xx1), 0.0f);
    float ih = fmaxf(__fsub_rn(yy2, yy1), 0.0f);
    float inter = __fmul_rn(iw, ih);
    float uni = __fsub_rn(__fadd_rn(iar, jar), inter);
    return (uni > 0.0f && __fadd_rn(inter, inter) > uni) ? 1 : 0;
}

__device__ __forceinline__ int iou_hit_div(float ix1, float iy1, float ix2, float iy2, float iar,
                                           float jx1, float jy1, float jx2, float jy2, float jar)
{
    float xx1 = fmaxf(ix1, jx1), yy1 = fmaxf(iy1, jy1);
    float xx2 = fminf(ix2, jx2), yy2 = fminf(iy2, jy2);
    float iw = fmaxf(__fsub_rn(xx2, xx1), 0.0f);
    float ih = fmaxf(__fsub_rn(yy2, yy1), 0.0f);
    float inter = __fmul_rn(iw, ih);
    float uni = __fsub_rn(__fadd_rn(iar, jar), inter);
    return (uni > 0.0f && __fdiv_rn(inter, uni) > 0.5f) ? 1 : 0;
}

// ---------------------------------------------------------------------------
// Dispatch 1: k_sort, 16 blocks x 256. Each block redundantly computes masks
// (batched loads, L2-shared) + prefix + compacts keys to LDS, then ranks its
// own 64 candidates: wave wv partial-ranks them over chunks {wv, wv+4, ...}
// via readlane broadcast; LDS-reduce the 4 partials; wave 0 decodes+scatters
// sorted float4 boxes + scores. Block 0 writes M (slow path: publishes keys).
// ---------------------------------------------------------------------------
__global__ void __launch_bounds__(256) k_sort(
    const float* __restrict__ x,
    float* __restrict__ gss, float4* __restrict__ gbox,
    u64* __restrict__ skeys, int* __restrict__ counter, int ws_ok)
{
    __shared__ u64 lmask[NCH];
    __shared__ int pc[NCH], loff[NCH];
    __shared__ int sM;
    __shared__ u64 kdb[FAST_CAP];
    __shared__ int prank[256];

    const int tid = threadIdx.x;
    const int lane = tid & 63;
    const int wv = tid >> 6;                  // 4 waves; 36 chunks each
    const int b = blockIdx.x;

    // ---- mask pass: wave wv owns chunks [wv*36, wv*36+36), 6-deep batches ----
    #pragma unroll
    for (int g = 0; g < 36; g += 6) {
        float sv[6];
        #pragma unroll
        for (int u = 0; u < 6; ++u)
            sv[u] = x[((wv * 36 + g + u) << 6) + lane];
        #pragma unroll
        for (int u = 0; u < 6; ++u) {
            u64 m = __ballot(sv[u] > PROB_THR);
            if (lane == 0) lmask[wv * 36 + g + u] = m;
        }
    }
    __syncthreads();
    if (tid < NCH) pc[tid] = __popcll(lmask[tid]);
    __syncthreads();
    if (tid < 64) {                           // wave-parallel prefix (validated)
        int acc = 0;
        for (int seg = 0; seg < 3; ++seg) {
            int c = (seg << 6) + lane;
            int pv = (c < NCH) ? pc[c] : 0;
            int v = pv;
            #pragma unroll
            for (int off = 1; off < 64; off <<= 1) {
                int u = __shfl_up(v, off);
                if (lane >= off) v += u;
            }
            if (c < NCH) loff[c] = acc + v - pv;
            acc += __shfl(v, 63);
        }
        if (lane == 0) sM = acc;
    }
    __syncthreads();
    const int M = sM;
    const bool fast = (M <= FAST_CAP) && ws_ok;
    if (b == 0 && tid == 0) counter[0] = M;

    if (!fast) {
        if (b == 0) {                         // publish compacted keys for slow path
            for (int c = wv; c < NCH; c += 4) {
                float s = x[(c << 6) + lane];
                u64 m = lmask[c];
                if ((m >> lane) & 1ull) {
                    int pos = loff[c] + __popcll(m & ((1ull << lane) - 1ull));
                    int n = (c << 6) + lane;
                    skeys[pos] = ((u64)__float_as_uint(s) << 32) | (u64)(NB - 1 - n);
                }
            }
        }
        return;
    }

    // ---- compact keys into LDS (key = score-bits<<32 | NB-1-n : unique) ----
    for (int c = wv; c < NCH; c += 4) {
        float s = x[(c << 6) + lane];          // L1-warm
        u64 m = lmask[c];
        if ((m >> lane) & 1ull) {
            int pos = loff[c] + __popcll(m & ((1ull << lane) - 1ull));
            int n = (c << 6) + lane;
            kdb[pos] = ((u64)__float_as_uint(s) << 32) | (u64)(NB - 1 - n);
        }
    }
    for (int q = M + tid; q < FAST_CAP; q += 256) kdb[q] = 0ull;  // pad
    __syncthreads();

    // ---- partitioned rank: candidate = b*64 + lane (same for all 4 waves) ----
    const int cand = (b << 6) + lane;          // < 1024 always
    const u64 k0 = kdb[cand];
    // prefetch decode inputs (wave 0's values are the ones consumed)
    const int n0 = NB - 1 - (int)(k0 & 0xFFFFFFFFull);
    float xv0 = x[NB + n0], yv0 = x[2 * NB + n0];
    float wv0 = x[3 * NB + n0], hv0 = x[4 * NB + n0];
    int r = 0;
    const int nck = (M + 63) >> 6;
    for (int ch = wv; ch < nck; ch += 4) {     // wave-uniform chunk slice
        u64 kq = kdb[(ch << 6) + lane];
        u32 qlo = (u32)kq, qhi = (u32)(kq >> 32);
        #pragma unroll
        for (int i = 0; i < 64; ++i) {
            u32 blo = (u32)__builtin_amdgcn_readlane((int)qlo, i);
            u32 bhi = (u32)__builtin_amdgcn_readlane((int)qhi, i);
            u64 kb = ((u64)bhi << 32) | (u64)blo;
            r += (kb > k0) ? 1 : 0;
        }
    }
    prank[tid] = r;
    __syncthreads();
    if (tid < 64 && cand < M) {
        int rk = prank[tid] + prank[64 + tid] + prank[128 + tid] + prank[192 + tid];
        float X1, Y1, X2, Y2;
        decode_core(n0, xv0, yv0, wv0, hv0, X1, Y1, X2, Y2);
        gbox[rk] = make_float4(X1, Y1, X2, Y2);
        gss[rk] = __uint_as_float((u32)(k0 >> 32));
    }
}

// ---------------------------------------------------------------------------
// Dispatch 2: k_adj, 64 blocks x 256 (R9/R10-validated). Zero-fill out slice;
// stage sorted boxes + areas into LDS; build 16 adjacency rows/block; write
// adjT[word][row].
// ---------------------------------------------------------------------------
__global__ void __launch_bounds__(256) k_adj(
    float* __restrict__ out, const float4* __restrict__ gbox,
    const int* __restrict__ counter, u64* __restrict__ adjT, int ws_ok)
{
    __shared__ float4 lb[FAST_CAP];
    __shared__ float la[FAST_CAP];
    int M = counter[0]; if (M > NB) M = NB;
    const int tid = threadIdx.x, lane = tid & 63, wv = tid >> 6, b = blockIdx.x;

    float4 z4 = make_float4(0.f, 0.f, 0.f, 0.f);
    for (int q = tid; q < 216; q += 256)       // 64*216 = 13824 float4 = whole out
        ((float4*)out)[b * 216 + q] = z4;

    const bool fast = (M <= FAST_CAP) && ws_ok;
    if (!fast) return;
    if ((b << 4) >= M) return;

    const int W = (M + 63) >> 6;
    for (int f = tid; f < M; f += 256) {
        float4 bb = gbox[f];
        lb[f] = bb;
        la[f] = __fmul_rn(__fsub_rn(bb.z, bb.x), __fsub_rn(bb.w, bb.y));
    }
    __syncthreads();

    #pragma unroll
    for (int r = 0; r < 4; ++r) {
        int i = (b << 4) + (r << 2) + wv;
        if (i >= M) break;
        float4 bi = lb[i];
        float iar = la[i];
        for (int kk = 0; kk < W; ++kk) {
            int j = (kk << 6) + lane;
            float4 bj = lb[j & (FAST_CAP - 1)];
            float jar = la[j & (FAST_CAP - 1)];
            int hit = (j < M) && iou_hit_nodiv(bi.x, bi.y, bi.z, bi.w, iar,
                                               bj.x, bj.y, bj.z, bj.w, jar);
            u64 mm = __ballot(hit);
            if (lane == 0) adjT[((size_t)kk << 10) + i] = mm;
        }
    }
}

// ---------------------------------------------------------------------------
// Dispatch 3: k_sweep, 1 block x 1024. Stage adjT -> LDS in ONE 8-deep
// batched round. Wave 0 sweeps: per 32-row block the decision chain uses only
// the uniform column words (colb); the suppression-OR (rowb) is deferred to
// KEPT rows only (independent b64 LDS reads). sup is consumed only at word
// boundaries, so deferral is algebraically identical to R8/R9. Emit kept
// rows only (out pre-zeroed by k_adj).
// ---------------------------------------------------------------------------
__global__ void __launch_bounds__(1024) k_sweep(
    const float* __restrict__ x, float* __restrict__ out,
    float* __restrict__ gss, float4* __restrict__ gbox,
    const u64* __restrict__ skeys, const int* __restrict__ counter,
    const u64* __restrict__ adjT, int ws_ok)
{
    __shared__ __align__(16) u64 Lds[16 * LSTRIDE];   // 132,352 B
    __shared__ u64 keepw[NCH];
    int M = counter[0]; if (M > NB) M = NB;
    const int W = (M + 63) >> 6;
    const bool fast = (M <= FAST_CAP) && ws_ok;
    const int tid = threadIdx.x, lane = tid & 63;

    if (fast) {
        // ---- stage adjT -> LDS, single 8-deep batched round ----
        const int npair = W << 9;                     // <= 8192 ulonglong2
        const ulonglong2* gp = (const ulonglong2*)adjT;
        ulonglong2 v[8];
        #pragma unroll
        for (int u = 0; u < 8; ++u) {
            int f = tid + (u << 10);
            v[u] = (f < npair) ? gp[f] : make_ulonglong2(0ull, 0ull);
        }
        #pragma unroll
        for (int u = 0; u < 8; ++u) {
            int f = tid + (u << 10);
            if (f < npair) {
                int w = f >> 9, r2 = f & 511;
                ((ulonglong2*)Lds)[w * (LSTRIDE >> 1) + r2] = v[u];
            }
        }
        __syncthreads();

        if (tid < 64) {
            const int wl = (lane < W) ? lane : 0;
            u32 supl = 0u, suph = 0u, dl = 0u, dh = 0u;
            u64 mykw = 0ull;
            const int nrb = (M + 31) >> 5;
            for (int rb = 0; rb < nrb; ++rb) {
                const int c = rb >> 1;
                const int base = rb << 5;
                const u64* crow = Lds + (size_t)c * LSTRIDE + base;   // uniform
                const u64* rrow = Lds + (size_t)wl * LSTRIDE + base;  // per-lane
                if (!(rb & 1)) {
                    if (rb == 0) { dl = 0u; dh = 0u; }
                    else { dl = (u32)__shfl((int)supl, c); dh = (u32)__shfl((int)suph, c); }
                    int rem = M - (c << 6);           // tail: rows >= M suppressed
                    if (rem < 64) {
                        if (rem >= 32) dh |= 0xFFFFFFFFu << (rem - 32);
                        else { dh = 0xFFFFFFFFu; dl |= 0xFFFFFFFFu << rem; }
                    }
                }
                // 32 uniform column words (broadcast b128 reads)
                u64 colb[32];
                #pragma unroll
                for (int q = 0; q < 16; ++q) {
                    ulonglong2 t2 = ((const ulonglong2*)crow)[q];
                    colb[2 * q] = t2.x; colb[2 * q + 1] = t2.y;
                }
                u32 kw = 0u;
                if (!(rb & 1)) {
                    #pragma unroll
                    for (int t = 0; t < 32; ++t) {
                        u32 bbit = (dl >> t) & 1u;
                        u32 m = bbit - 1u;            // ~0 kept, 0 suppressed
                        dl |= (u32)colb[t] & m;
                        dh |= (u32)(colb[t] >> 32) & m;
                        kw |= m & (1u << t);
                    }
                } else {
                    #pragma unroll
                    for (int t = 0; t < 32; ++t) {
                        u32 bbit = (dh >> t) & 1u;
                        u32 m = bbit - 1u;
                        dl |= (u32)colb[t] & m;
                        dh |= (u32)(colb[t] >> 32) & m;
                        kw |= m & (1u << t);
                    }
                }
                // deferred suppression-OR over kept rows only
                u32 bits = kw;
                while (bits) {
                    int t = __builtin_ctz(bits);
                    bits &= bits - 1u;
                    u64 rv = rrow[t];
                    supl |= (u32)rv;
                    suph |= (u32)(rv >> 32);
                }
                mykw |= (lane == c) ? ((u64)kw << ((rb & 1) << 5)) : 0ull;
            }
            keepw[lane] = mykw;
        }
    } else {
        // slow path (M > 1024): counting rank from skeys + decode + scatter,
        // then single-wave on-the-fly sweep (validated logic).
        for (int t = tid; t < M; t += 1024) {
            u64 key = skeys[t];
            int r = 0;
            for (int q = 0; q < M; ++q) r += (skeys[q] > key) ? 1 : 0;
            int n = NB - 1 - (int)(key & 0xFFFFFFFFull);
            float X1, Y1, X2, Y2;
            decode_box(x, n, X1, Y1, X2, Y2);
            gbox[r] = make_float4(X1, Y1, X2, Y2);
            gss[r] = __uint_as_float((u32)(key >> 32));
        }
        __threadfence();
        __syncthreads();
        if (tid < 64) {
            u64 kbs[3] = {0ull, 0ull, 0ull};
            for (int i = 0; i < M; ++i) {
                float4 bi = gbox[i];
                float iar = __fmul_rn(__fsub_rn(bi.z, bi.x), __fsub_rn(bi.w, bi.y));
                int hit = 0;
                int nk = (i > lane) ? ((i - lane + 63) >> 6) : 0;
                for (int w = 0; w < 3 && !hit; ++w) {
                    int klim = nk - (w << 6);
                    if (klim <= 0) break;
                    u64 bits = kbs[w];
                    if (klim < 64) bits &= ((1ull << klim) - 1ull);
                    while (bits) {
                        int kk2 = __builtin_ctzll(bits);
                        bits &= bits - 1ull;
                        int jj = lane + (((w << 6) + kk2) << 6);
                        float4 bj = gbox[jj];
                        float jar = __fmul_rn(__fsub_rn(bj.z, bj.x), __fsub_rn(bj.w, bj.y));
                        if (iou_hit_div(bi.x, bi.y, bi.z, bi.w, iar,
                                        bj.x, bj.y, bj.z, bj.w, jar)) { hit = 1; break; }
                    }
                }
                int suppressed = __any(hit);
                if (!suppressed && lane == (i & 63)) kbs[(i >> 6) >> 6] |= 1ull << ((i >> 6) & 63);
            }
            int NWrd = (M + 63) >> 6;
            for (int wd = 0; wd < NWrd; ++wd) {
                u64 bit = (kbs[wd >> 6] >> (wd & 63)) & 1ull;
                u64 word = __ballot(bit != 0);
                if (lane == 0 && wd < NCH) keepw[wd] = word;
            }
        }
    }
    __syncthreads();

    // emit kept rows only (rest pre-zeroed by k_adj)
    for (int i = tid; i < M; i += 1024) {
        if ((keepw[i >> 6] >> (i & 63)) & 1ull) {
            float4 bb = gbox[i];
            out[i * 5 + 0] = gss[i];
            out[i * 5 + 1] = bb.x;
            out[i * 5 + 2] = bb.y;
            out[i * 5 + 3] = __fsub_rn(bb.z, bb.x);
            out[i * 5 + 4] = __fsub_rn(bb.w, bb.y);
            out[5 * NB + i] = 1.0f;
        }
    }
}

extern "C" void kernel_launch(void* const* d_in, const int* in_sizes, int n_in,
                              void* d_out, int out_size, void* d_ws, size_t ws_size,
                              hipStream_t stream) {
    const float* x = (const float*)d_in[0];
    float* out = (float*)d_out;

    // Workspace: counter 16 | gss f32[NB] | gbox float4[NB] | adjT u64[16*1024]
    // | skeys u64[NB]
    char* ws = (char*)d_ws;
    int* counter = (int*)ws;
    float*  gss  = (float*)(ws + 16);
    float4* gbox = (float4*)(ws + 16 + (size_t)4 * NB);
    u64*    adjT = (u64*)(ws + 16 + (size_t)4 * NB + (size_t)16 * NB);
    u64*    skeys = (u64*)((char*)adjT + (size_t)16384 * 8);
    const size_t NEEDED = 16 + (size_t)4 * NB + (size_t)16 * NB
                        + (size_t)16384 * 8 + (size_t)8 * NB;      // 389,136
    int ws_ok = (ws_size >= NEEDED) ? 1 : 0;

    k_sort<<<16, 256, 0, stream>>>(x, gss, gbox, skeys, counter, ws_ok);
    k_adj<<<64, 256, 0, stream>>>(out, gbox, counter, adjT, ws_ok);
    k_sweep<<<1, 1024, 0, stream>>>(x, out, gss, gbox, skeys, counter, adjT, ws_ok);
}

// Round 12
// 103.538 us; speedup vs baseline: 2.4627x; 1.0849x over previous
//
#include <hip/hip_runtime.h>

#define PP 96
#define NB (PP*PP)            // 9216
#define NCH (NB/64)           // 144 64-chunks
#define PROB_THR 0.9f
#define FAST_CAP 1024         // fast path: M <= 1024, W <= 16
#define LSTRIDE 1034          // padded LDS row stride (u64): even (16B), 2-way max aliasing

typedef unsigned long long u64;
typedef unsigned int u32;

// Bit-identical decode core (no FMA contraction; rintf == round-half-even).
__device__ __forceinline__ void decode_core(int n, float xv, float yv, float wv, float hv,
                                            float& X1, float& Y1, float& X2, float& Y2)
{
    int i = n / PP;
    int j = n - i * PP;
    float bx = __fadd_rn(__fmul_rn(xv, 16.0f), (float)i * 16.0f);
    float by = __fadd_rn(__fmul_rn(yv, 16.0f), (float)j * 16.0f);
    float bw = __fmul_rn(wv, 1536.0f);
    float bh = __fmul_rn(hv, 1536.0f);
    X1 = rintf(bx);
    Y1 = rintf(by);
    X2 = rintf(__fadd_rn(bw, bx));
    Y2 = rintf(__fadd_rn(bh, by));
}

__device__ __forceinline__ void decode_box(const float* __restrict__ x, int n,
                                           float& X1, float& Y1, float& X2, float& Y2)
{
    decode_core(n, x[NB + n], x[2 * NB + n], x[3 * NB + n], x[4 * NB + n], X1, Y1, X2, Y2);
}

// Exact-equivalent IoU>0.5 without division (R5-R10 validated on HW).
__device__ __forceinline__ int iou_hit_nodiv(float ix1, float iy1, float ix2, float iy2, float iar,
                                             float jx1, float jy1, float jx2, float jy2, float jar)
{
    float xx1 = fmaxf(ix1, jx1), yy1 = fmaxf(iy1, jy1);
    float xx2 = fminf(ix2, jx2), yy2 = fminf(iy2, jy2);
    float iw = fmaxf(__fsub_rn(xx2, xx1), 0.0f);
    float ih = fmaxf(__fsub_rn(yy2, yy1), 0.0f);
    float inter = __fmul_rn(iw, ih);
    float uni = __fsub_rn(__fadd_rn(iar, jar), inter);
    return (uni > 0.0f && __fadd_rn(inter, inter) > uni) ? 1 : 0;
}

__device__ __forceinline__ int iou_hit_div(float ix1, float iy1, float ix2, float iy2, float iar,
                                           float jx1, float jy1, float jx2, float jy2, float jar)
{
    float xx1 = fmaxf(ix1, jx1), yy1 = fmaxf(iy1, jy1);
    float xx2 = fminf(ix2, jx2), yy2 = fminf(iy2, jy2);
    float iw = fmaxf(__fsub_rn(xx2, xx1), 0.0f);
    float ih = fmaxf(__fsub_rn(yy2, yy1), 0.0f);
    float inter = __fmul_rn(iw, ih);
    float uni = __fsub_rn(__fadd_rn(iar, jar), inter);
    return (uni > 0.0f && __fdiv_rn(inter, uni) > 0.5f) ? 1 : 0;
}

// ---------------------------------------------------------------------------
// Dispatch 1: k_sort, 16 blocks x 256 (R10-validated). Redundant mask/prefix/
// compact; each block ranks its own 64 candidates (4 waves partial-rank via
// readlane broadcast + LDS reduce); wave 0 decodes + scatters.
// ---------------------------------------------------------------------------
__global__ void __launch_bounds__(256) k_sort(
    const float* __restrict__ x,
    float* __restrict__ gss, float4* __restrict__ gbox,
    u64* __restrict__ skeys, int* __restrict__ counter, int ws_ok)
{
    __shared__ u64 lmask[NCH];
    __shared__ int pc[NCH], loff[NCH];
    __shared__ int sM;
    __shared__ u64 kdb[FAST_CAP];
    __shared__ int prank[256];

    const int tid = threadIdx.x;
    const int lane = tid & 63;
    const int wv = tid >> 6;                  // 4 waves; 36 chunks each
    const int b = blockIdx.x;

    #pragma unroll
    for (int g = 0; g < 36; g += 6) {
        float sv[6];
        #pragma unroll
        for (int u = 0; u < 6; ++u)
            sv[u] = x[((wv * 36 + g + u) << 6) + lane];
        #pragma unroll
        for (int u = 0; u < 6; ++u) {
            u64 m = __ballot(sv[u] > PROB_THR);
            if (lane == 0) lmask[wv * 36 + g + u] = m;
        }
    }
    __syncthreads();
    if (tid < NCH) pc[tid] = __popcll(lmask[tid]);
    __syncthreads();
    if (tid < 64) {                           // wave-parallel prefix (validated)
        int acc = 0;
        for (int seg = 0; seg < 3; ++seg) {
            int c = (seg << 6) + lane;
            int pv = (c < NCH) ? pc[c] : 0;
            int v = pv;
            #pragma unroll
            for (int off = 1; off < 64; off <<= 1) {
                int u = __shfl_up(v, off);
                if (lane >= off) v += u;
            }
            if (c < NCH) loff[c] = acc + v - pv;
            acc += __shfl(v, 63);
        }
        if (lane == 0) sM = acc;
    }
    __syncthreads();
    const int M = sM;
    const bool fast = (M <= FAST_CAP) && ws_ok;
    if (b == 0 && tid == 0) counter[0] = M;

    if (!fast) {
        if (b == 0) {
            for (int c = wv; c < NCH; c += 4) {
                float s = x[(c << 6) + lane];
                u64 m = lmask[c];
                if ((m >> lane) & 1ull) {
                    int pos = loff[c] + __popcll(m & ((1ull << lane) - 1ull));
                    int n = (c << 6) + lane;
                    skeys[pos] = ((u64)__float_as_uint(s) << 32) | (u64)(NB - 1 - n);
                }
            }
        }
        return;
    }

    for (int c = wv; c < NCH; c += 4) {
        float s = x[(c << 6) + lane];          // L1-warm
        u64 m = lmask[c];
        if ((m >> lane) & 1ull) {
            int pos = loff[c] + __popcll(m & ((1ull << lane) - 1ull));
            int n = (c << 6) + lane;
            kdb[pos] = ((u64)__float_as_uint(s) << 32) | (u64)(NB - 1 - n);
        }
    }
    for (int q = M + tid; q < FAST_CAP; q += 256) kdb[q] = 0ull;  // pad
    __syncthreads();

    const int cand = (b << 6) + lane;          // < 1024 always
    const u64 k0 = kdb[cand];
    const int n0 = NB - 1 - (int)(k0 & 0xFFFFFFFFull);
    float xv0 = x[NB + n0], yv0 = x[2 * NB + n0];
    float wv0 = x[3 * NB + n0], hv0 = x[4 * NB + n0];
    int r = 0;
    const int nck = (M + 63) >> 6;
    for (int ch = wv; ch < nck; ch += 4) {     // wave-uniform chunk slice
        u64 kq = kdb[(ch << 6) + lane];
        u32 qlo = (u32)kq, qhi = (u32)(kq >> 32);
        #pragma unroll
        for (int i = 0; i < 64; ++i) {
            u32 blo = (u32)__builtin_amdgcn_readlane((int)qlo, i);
            u32 bhi = (u32)__builtin_amdgcn_readlane((int)qhi, i);
            u64 kb = ((u64)bhi << 32) | (u64)blo;
            r += (kb > k0) ? 1 : 0;
        }
    }
    prank[tid] = r;
    __syncthreads();
    if (tid < 64 && cand < M) {
        int rk = prank[tid] + prank[64 + tid] + prank[128 + tid] + prank[192 + tid];
        float X1, Y1, X2, Y2;
        decode_core(n0, xv0, yv0, wv0, hv0, X1, Y1, X2, Y2);
        gbox[rk] = make_float4(X1, Y1, X2, Y2);
        gss[rk] = __uint_as_float((u32)(k0 >> 32));
    }
}

// ---------------------------------------------------------------------------
// Dispatch 2: k_adj, 64 blocks x 256 (R9/R10-validated).
// ---------------------------------------------------------------------------
__global__ void __launch_bounds__(256) k_adj(
    float* __restrict__ out, const float4* __restrict__ gbox,
    const int* __restrict__ counter, u64* __restrict__ adjT, int ws_ok)
{
    __shared__ float4 lb[FAST_CAP];
    __shared__ float la[FAST_CAP];
    int M = counter[0]; if (M > NB) M = NB;
    const int tid = threadIdx.x, lane = tid & 63, wv = tid >> 6, b = blockIdx.x;

    float4 z4 = make_float4(0.f, 0.f, 0.f, 0.f);
    for (int q = tid; q < 216; q += 256)       // 64*216 = whole out
        ((float4*)out)[b * 216 + q] = z4;

    const bool fast = (M <= FAST_CAP) && ws_ok;
    if (!fast) return;
    if ((b << 4) >= M) return;

    const int W = (M + 63) >> 6;
    for (int f = tid; f < M; f += 256) {
        float4 bb = gbox[f];
        lb[f] = bb;
        la[f] = __fmul_rn(__fsub_rn(bb.z, bb.x), __fsub_rn(bb.w, bb.y));
    }
    __syncthreads();

    #pragma unroll
    for (int r = 0; r < 4; ++r) {
        int i = (b << 4) + (r << 2) + wv;
        if (i >= M) break;
        float4 bi = lb[i];
        float iar = la[i];
        for (int kk = 0; kk < W; ++kk) {
            int j = (kk << 6) + lane;
            float4 bj = lb[j & (FAST_CAP - 1)];
            float jar = la[j & (FAST_CAP - 1)];
            int hit = (j < M) && iou_hit_nodiv(bi.x, bi.y, bi.z, bi.w, iar,
                                               bj.x, bj.y, bj.z, bj.w, jar);
            u64 mm = __ballot(hit);
            if (lane == 0) adjT[((size_t)kk << 10) + i] = mm;
        }
    }
}

// ---------------------------------------------------------------------------
// Dispatch 3: k_sweep, 1 block x 256 (1 wave/SIMD -> full VGPR budget; R10's
// 1024-thread launch capped VGPRs at 52 and forced just-in-time serialized
// ds_reads, 44 us). Per 32-row block: batch 16+16 independent ds_read_b128
// into colb[32]/rowb[32] REGISTERS (one wait), pure-ALU decision chain on
// colb, then constant-trip MASKED suppression-OR over rowb (replaces R10's
// serial while-loop). Emit kept rows only.
// ---------------------------------------------------------------------------
__global__ void __launch_bounds__(256) k_sweep(
    const float* __restrict__ x, float* __restrict__ out,
    float* __restrict__ gss, float4* __restrict__ gbox,
    const u64* __restrict__ skeys, const int* __restrict__ counter,
    const u64* __restrict__ adjT, int ws_ok)
{
    __shared__ __align__(16) u64 Lds[16 * LSTRIDE];   // 132,352 B
    __shared__ u64 keepw[NCH];
    int M = counter[0]; if (M > NB) M = NB;
    const int W = (M + 63) >> 6;
    const bool fast = (M <= FAST_CAP) && ws_ok;
    const int tid = threadIdx.x, lane = tid & 63;

    if (fast) {
        // ---- stage adjT -> LDS: 4 rounds x 8-deep batched 16B (R9-validated) ----
        const int npair = W << 9;                     // <= 8192 ulonglong2
        const ulonglong2* gp = (const ulonglong2*)adjT;
        for (int r = 0; r < 4; ++r) {
            int fb = (r << 11) + tid;
            ulonglong2 v[8];
            #pragma unroll
            for (int u = 0; u < 8; ++u) {
                int f = fb + (u << 8);
                v[u] = (f < npair) ? gp[f] : make_ulonglong2(0ull, 0ull);
            }
            #pragma unroll
            for (int u = 0; u < 8; ++u) {
                int f = fb + (u << 8);
                if (f < npair) {
                    int w = f >> 9, r2 = f & 511;
                    ((ulonglong2*)Lds)[w * (LSTRIDE >> 1) + r2] = v[u];
                }
            }
        }
        __syncthreads();

        if (tid < 64) {
            const int wl = (lane < W) ? lane : 0;
            u32 supl = 0u, suph = 0u, dl = 0u, dh = 0u;
            u64 mykw = 0ull;
            const int nrb = (M + 31) >> 5;
            for (int rb = 0; rb < nrb; ++rb) {
                const int c = rb >> 1;
                const int base = rb << 5;
                const ulonglong2* crow = (const ulonglong2*)(Lds + (size_t)c * LSTRIDE + base);
                const ulonglong2* rrow = (const ulonglong2*)(Lds + (size_t)wl * LSTRIDE + base);
                // batch-issue BOTH columns as 32 independent b128 reads -> regs
                u64 colb[32], rowb[32];
                #pragma unroll
                for (int q = 0; q < 16; ++q) {
                    ulonglong2 t2 = crow[q];
                    colb[2 * q] = t2.x; colb[2 * q + 1] = t2.y;
                }
                #pragma unroll
                for (int q = 0; q < 16; ++q) {
                    ulonglong2 t2 = rrow[q];
                    rowb[2 * q] = t2.x; rowb[2 * q + 1] = t2.y;
                }
                if (!(rb & 1)) {
                    if (rb == 0) { dl = 0u; dh = 0u; }
                    else { dl = (u32)__shfl((int)supl, c); dh = (u32)__shfl((int)suph, c); }
                    int rem = M - (c << 6);           // tail: rows >= M suppressed
                    if (rem < 64) {
                        if (rem >= 32) dh |= 0xFFFFFFFFu << (rem - 32);
                        else { dh = 0xFFFFFFFFu; dl |= 0xFFFFFFFFu << rem; }
                    }
                }
                u32 kw = 0u;
                if (!(rb & 1)) {
                    #pragma unroll
                    for (int t = 0; t < 32; ++t) {
                        u32 bbit = (dl >> t) & 1u;
                        u32 m = bbit - 1u;            // ~0 kept, 0 suppressed
                        dl |= (u32)colb[t] & m;
                        dh |= (u32)(colb[t] >> 32) & m;
                        kw |= m & (1u << t);
                    }
                } else {
                    #pragma unroll
                    for (int t = 0; t < 32; ++t) {
                        u32 bbit = (dh >> t) & 1u;
                        u32 m = bbit - 1u;
                        dl |= (u32)colb[t] & m;
                        dh |= (u32)(colb[t] >> 32) & m;
                        kw |= m & (1u << t);
                    }
                }
                // constant-trip masked suppression-OR (values already in regs)
                #pragma unroll
                for (int t = 0; t < 32; ++t) {
                    u32 m = 0u - ((kw >> t) & 1u);    // ~0 if kept
                    supl |= (u32)rowb[t] & m;
                    suph |= (u32)(rowb[t] >> 32) & m;
                }
                mykw |= (lane == c) ? ((u64)kw << ((rb & 1) << 5)) : 0ull;
            }
            keepw[lane] = mykw;
        }
    } else {
        // slow path (M > 1024): counting rank + decode + single-wave sweep.
        for (int t = tid; t < M; t += 256) {
            u64 key = skeys[t];
            int r = 0;
            for (int q = 0; q < M; ++q) r += (skeys[q] > key) ? 1 : 0;
            int n = NB - 1 - (int)(key & 0xFFFFFFFFull);
            float X1, Y1, X2, Y2;
            decode_box(x, n, X1, Y1, X2, Y2);
            gbox[r] = make_float4(X1, Y1, X2, Y2);
            gss[r] = __uint_as_float((u32)(key >> 32));
        }
        __threadfence();
        __syncthreads();
        if (tid < 64) {
            u64 kbs[3] = {0ull, 0ull, 0ull};
            for (int i = 0; i < M; ++i) {
                float4 bi = gbox[i];
                float iar = __fmul_rn(__fsub_rn(bi.z, bi.x), __fsub_rn(bi.w, bi.y));
                int hit = 0;
                int nk = (i > lane) ? ((i - lane + 63) >> 6) : 0;
                for (int w = 0; w < 3 && !hit; ++w) {
                    int klim = nk - (w << 6);
                    if (klim <= 0) break;
                    u64 bits = kbs[w];
                    if (klim < 64) bits &= ((1ull << klim) - 1ull);
                    while (bits) {
                        int kk2 = __builtin_ctzll(bits);
                        bits &= bits - 1ull;
                        int jj = lane + (((w << 6) + kk2) << 6);
                        float4 bj = gbox[jj];
                        float jar = __fmul_rn(__fsub_rn(bj.z, bj.x), __fsub_rn(bj.w, bj.y));
                        if (iou_hit_div(bi.x, bi.y, bi.z, bi.w, iar,
                                        bj.x, bj.y, bj.z, bj.w, jar)) { hit = 1; break; }
                    }
                }
                int suppressed = __any(hit);
                if (!suppressed && lane == (i & 63)) kbs[(i >> 6) >> 6] |= 1ull << ((i >> 6) & 63);
            }
            int NWrd = (M + 63) >> 6;
            for (int wd = 0; wd < NWrd; ++wd) {
                u64 bit = (kbs[wd >> 6] >> (wd & 63)) & 1ull;
                u64 word = __ballot(bit != 0);
                if (lane == 0 && wd < NCH) keepw[wd] = word;
            }
        }
    }
    __syncthreads();

    // emit kept rows only (rest pre-zeroed by k_adj)
    for (int i = tid; i < M; i += 256) {
        if ((keepw[i >> 6] >> (i & 63)) & 1ull) {
            float4 bb = gbox[i];
            out[i * 5 + 0] = gss[i];
            out[i * 5 + 1] = bb.x;
            out[i * 5 + 2] = bb.y;
            out[i * 5 + 3] = __fsub_rn(bb.z, bb.x);
            out[i * 5 + 4] = __fsub_rn(bb.w, bb.y);
            out[5 * NB + i] = 1.0f;
        }
    }
}

extern "C" void kernel_launch(void* const* d_in, const int* in_sizes, int n_in,
                              void* d_out, int out_size, void* d_ws, size_t ws_size,
                              hipStream_t stream) {
    const float* x = (const float*)d_in[0];
    float* out = (float*)d_out;

    char* ws = (char*)d_ws;
    int* counter = (int*)ws;
    float*  gss  = (float*)(ws + 16);
    float4* gbox = (float4*)(ws + 16 + (size_t)4 * NB);
    u64*    adjT = (u64*)(ws + 16 + (size_t)4 * NB + (size_t)16 * NB);
    u64*    skeys = (u64*)((char*)adjT + (size_t)16384 * 8);
    const size_t NEEDED = 16 + (size_t)4 * NB + (size_t)16 * NB
                        + (size_t)16384 * 8 + (size_t)8 * NB;      // 389,136
    int ws_ok = (ws_size >= NEEDED) ? 1 : 0;

    k_sort<<<16, 256, 0, stream>>>(x, gss, gbox, skeys, counter, ws_ok);
    k_adj<<<64, 256, 0, stream>>>(out, gbox, counter, adjT, ws_ok);
    k_sweep<<<1, 256, 0, stream>>>(x, out, gss, gbox, skeys, counter, adjT, ws_ok);
}